// Round 1
// baseline (1497.455 us; speedup 1.0000x reference)
//
#include <hip/hip_runtime.h>

typedef unsigned short u16;
typedef __attribute__((ext_vector_type(8))) short short8;
typedef __attribute__((ext_vector_type(4))) float f32x4;

#define NB_ 64

static __device__ __forceinline__ f32x4 mfma16(short8 a, short8 b, f32x4 c) {
  return __builtin_amdgcn_mfma_f32_16x16x32_bf16(a, b, c, 0, 0, 0);
}

// split fp32 -> bf16 hi + bf16 lo  (x ~= hi + lo, residual ~2^-17 * |x|)
static __device__ __forceinline__ void split_bf16(float x, u16& hi, u16& lo) {
  unsigned u = __float_as_uint(x);
  unsigned r = (u + 0x7fffu + ((u >> 16) & 1u)) >> 16;
  hi = (u16)r;
  float fh = __uint_as_float(r << 16);
  float xl = x - fh;
  unsigned ul = __float_as_uint(xl);
  unsigned rl2 = (ul + 0x7fffu + ((ul >> 16) & 1u)) >> 16;
  lo = (u16)rl2;
}

// ---------------- pooling: emb gather + mean over valid items ----------------
__global__ __launch_bounds__(128) void k_pool(const int* __restrict__ iv,
                                              const float* __restrict__ emb,
                                              u16* __restrict__ ebh, u16* __restrict__ ebl,
                                              float* __restrict__ cm) {
  int u = blockIdx.x;             // u = (s*2+t)*64+b
  int s = u >> 7;
  int t = (u >> 6) & 1;
  int b = u & 63;
  int d = threadIdx.x;
  const int ibase = ((t * 64 + b) * 30 + s) * 12;
  float sum = 0.f;
  int cnt = 0;
  for (int k = 0; k < 12; ++k) {
    int idx = iv[ibase + k];
    if (idx > 0) { cnt++; sum += emb[(size_t)idx * 128 + d]; }
  }
  float den = (cnt > 0) ? (float)cnt : 1.f;
  float v = sum / den;
  u16 hi, lo; split_bf16(v, hi, lo);
  ebh[(size_t)u * 128 + d] = hi;
  ebl[(size_t)u * 128 + d] = lo;
  if (d == 0) cm[u] = (cnt > 0) ? 1.f : 0.f;
}

// ---------------- weight swizzle into MFMA B-fragment layout ----------------
// B-frag (16x16x32): lane l holds B[k=(l>>4)*8+j][n=l&15], j=0..7
// w1 units: 64 blk * 20 ks * 2 nt  (ks 0..7: Wih h_meta part K=256; 8..15: Whh K=256; 16..19: Wih x part K=128)
//   block blk: t=blk>>5, hd0=(blk&31)*8; 24 real cols: [r:8][z:8][n:8], pad to 32
// w2 units: 64 blk * 24 ks (0..15: mWih K=512; 16..23: mWhh K=256); 12 real cols [r:4][z:4][n:4] pad 16
// wN units: 1256 ntile * 8 ks, cols = Wnew rows (pad past 20000)
__global__ __launch_bounds__(256) void k_swz(const float* __restrict__ Wih,
                                             const float* __restrict__ Whh,
                                             const float* __restrict__ mWih,
                                             const float* __restrict__ mWhh,
                                             const float* __restrict__ Wnew,
                                             u16* __restrict__ w1h, u16* __restrict__ w1l,
                                             u16* __restrict__ w2h, u16* __restrict__ w2l,
                                             u16* __restrict__ wnh, u16* __restrict__ wnl) {
  int gu = blockIdx.x * 4 + (threadIdx.x >> 6);
  int lane = threadIdx.x & 63;
  int ko = (lane >> 4) * 8;
  int cl = lane & 15;
  float src[8];
  if (gu < 2560) {
    int blk = gu / 40, r = gu % 40, ksIdx = r >> 1, nt = r & 1;
    int t = blk >> 5, hd0 = (blk & 31) * 8;
    int c = nt * 16 + cl;
    if (c < 24) {
      int gc = (c < 8) ? (hd0 + c) : (c < 16) ? (256 + hd0 + (c - 8)) : (512 + hd0 + (c - 16));
      const float* wrow; int kk;
      if (ksIdx < 8)       { wrow = Wih + (size_t)(t * 768 + gc) * 384 + 128; kk = ksIdx * 32 + ko; }
      else if (ksIdx < 16) { wrow = Whh + (size_t)(t * 768 + gc) * 256;       kk = (ksIdx - 8) * 32 + ko; }
      else                 { wrow = Wih + (size_t)(t * 768 + gc) * 384;       kk = (ksIdx - 16) * 32 + ko; }
      #pragma unroll
      for (int j = 0; j < 8; ++j) src[j] = wrow[kk + j];
    } else {
      #pragma unroll
      for (int j = 0; j < 8; ++j) src[j] = 0.f;
    }
    int off = gu * 512 + lane * 8;
    #pragma unroll
    for (int j = 0; j < 8; ++j) { u16 h, l; split_bf16(src[j], h, l); w1h[off + j] = h; w1l[off + j] = l; }
  } else if (gu < 4096) {
    int g2 = gu - 2560;
    int blk = g2 / 24, ksIdx = g2 % 24;
    int hd0 = blk * 4;
    int c = cl;
    if (c < 12) {
      int gc = (c < 4) ? (hd0 + c) : (c < 8) ? (256 + hd0 + (c - 4)) : (512 + hd0 + (c - 8));
      if (ksIdx < 16) {
        int kk = ksIdx * 32 + ko;
        #pragma unroll
        for (int j = 0; j < 8; ++j) src[j] = mWih[(size_t)gc * 512 + kk + j];
      } else {
        int kk = (ksIdx - 16) * 32 + ko;
        #pragma unroll
        for (int j = 0; j < 8; ++j) src[j] = mWhh[(size_t)gc * 256 + kk + j];
      }
    } else {
      #pragma unroll
      for (int j = 0; j < 8; ++j) src[j] = 0.f;
    }
    int off = g2 * 512 + lane * 8;
    #pragma unroll
    for (int j = 0; j < 8; ++j) { u16 h, l; split_bf16(src[j], h, l); w2h[off + j] = h; w2l[off + j] = l; }
  } else if (gu < 14144) {
    int g3 = gu - 4096;
    int gnt = g3 >> 3, ks = g3 & 7;
    int col = gnt * 16 + cl;
    if (col < 20000) {
      int kk = ks * 32 + ko;
      #pragma unroll
      for (int j = 0; j < 8; ++j) src[j] = Wnew[(size_t)col * 256 + kk + j];
    } else {
      #pragma unroll
      for (int j = 0; j < 8; ++j) src[j] = 0.f;
    }
    int off = g3 * 512 + lane * 8;
    #pragma unroll
    for (int j = 0; j < 8; ++j) { u16 h, l; split_bf16(src[j], h, l); wnh[off + j] = h; wnl[off + j] = l; }
  }
}

// ---------------- persistent GRU recurrence ----------------
static __device__ __forceinline__ void gridbar(int* bar, int& epoch) {
  __threadfence();
  __syncthreads();
  ++epoch;
  if (threadIdx.x == 0) {
    atomicAdd(bar, 1);
    while (__hip_atomic_load(bar, __ATOMIC_ACQUIRE, __HIP_MEMORY_SCOPE_AGENT) < epoch * NB_)
      __builtin_amdgcn_s_sleep(1);
  }
  __syncthreads();
  __threadfence();
}

__global__ __launch_bounds__(256) void k_rnn(
    const u16* __restrict__ ebh, const u16* __restrict__ ebl,
    const u16* __restrict__ w1h, const u16* __restrict__ w1l,
    const u16* __restrict__ w2h, const u16* __restrict__ w2l,
    const float* __restrict__ bih, const float* __restrict__ bhh,
    const float* __restrict__ mbih, const float* __restrict__ mbhh,
    const float* __restrict__ cm,
    float* __restrict__ hs, float* __restrict__ hms,
    u16* __restrict__ hhh, u16* __restrict__ hhl,
    u16* __restrict__ ahi, u16* __restrict__ alo,
    int* bar) {
  const int blk = blockIdx.x;
  const int tid = threadIdx.x;
  const int lane = tid & 63;
  const int w = tid >> 6;
  const int t1 = blk >> 5;
  const int hd1 = (blk & 31) * 8;
  const int hd2 = blk * 4;
  const int arow = w * 16 + (lane & 15);
  const int ko = (lane >> 4) * 8;
  int epoch = 0;

  __shared__ float ls_rz[4][16][16];
  __shared__ float ls_gi[4][16][8];
  __shared__ float ls_gh[4][16][8];

  for (int s = 0; s < 30; ++s) {
    // ---------- phase 1: task GRUs ----------
    f32x4 a1[2], a2[2], a3[2];
    #pragma unroll
    for (int i = 0; i < 2; ++i) {
      a1[i] = (f32x4){0.f, 0.f, 0.f, 0.f};
      a2[i] = (f32x4){0.f, 0.f, 0.f, 0.f};
      a3[i] = (f32x4){0.f, 0.f, 0.f, 0.f};
    }
    if (s > 0) {
      // G1: h_meta @ WihH   (A rows live in ahi/alo at row b*30+(s-1))
      const u16* Ah = ahi + (size_t)(arow * 30 + (s - 1)) * 256;
      const u16* Al = alo + (size_t)(arow * 30 + (s - 1)) * 256;
      #pragma unroll
      for (int ks = 0; ks < 8; ++ks) {
        short8 xh = *(const short8*)(Ah + ks * 32 + ko);
        short8 xl = *(const short8*)(Al + ks * 32 + ko);
        #pragma unroll
        for (int nt = 0; nt < 2; ++nt) {
          int un = (blk * 20 + ks) * 2 + nt;
          short8 bh = *(const short8*)(w1h + un * 512 + lane * 8);
          short8 bl = *(const short8*)(w1l + un * 512 + lane * 8);
          a1[nt] = mfma16(xh, bh, a1[nt]);
          a1[nt] = mfma16(xl, bh, a1[nt]);
          a1[nt] = mfma16(xh, bl, a1[nt]);
        }
      }
      // G2: h_task @ Whh
      const u16* Hh = hhh + (size_t)((s * 2 + t1) * 64 + arow) * 256;
      const u16* Hl = hhl + (size_t)((s * 2 + t1) * 64 + arow) * 256;
      #pragma unroll
      for (int ks = 0; ks < 8; ++ks) {
        short8 xh = *(const short8*)(Hh + ks * 32 + ko);
        short8 xl = *(const short8*)(Hl + ks * 32 + ko);
        #pragma unroll
        for (int nt = 0; nt < 2; ++nt) {
          int un = (blk * 20 + 8 + ks) * 2 + nt;
          short8 bh = *(const short8*)(w1h + un * 512 + lane * 8);
          short8 bl = *(const short8*)(w1l + un * 512 + lane * 8);
          a2[nt] = mfma16(xh, bh, a2[nt]);
          a2[nt] = mfma16(xl, bh, a2[nt]);
          a2[nt] = mfma16(xh, bl, a2[nt]);
        }
      }
    }
    {
      // G3: x @ WihX (K=128)
      const u16* Xh = ebh + (size_t)((s * 2 + t1) * 64 + arow) * 128;
      const u16* Xl = ebl + (size_t)((s * 2 + t1) * 64 + arow) * 128;
      #pragma unroll
      for (int ks = 0; ks < 4; ++ks) {
        short8 xh = *(const short8*)(Xh + ks * 32 + ko);
        short8 xl = *(const short8*)(Xl + ks * 32 + ko);
        #pragma unroll
        for (int nt = 0; nt < 2; ++nt) {
          int un = (blk * 20 + 16 + ks) * 2 + nt;
          short8 bh = *(const short8*)(w1h + un * 512 + lane * 8);
          short8 bl = *(const short8*)(w1l + un * 512 + lane * 8);
          a3[nt] = mfma16(xh, bh, a3[nt]);
          a3[nt] = mfma16(xl, bh, a3[nt]);
          a3[nt] = mfma16(xh, bl, a3[nt]);
        }
      }
    }
    // gate pre-activations -> LDS (C layout: row=(l>>4)*4+i, col=l&15)
    #pragma unroll
    for (int i = 0; i < 4; ++i) {
      int rl = (lane >> 4) * 4 + i;
      int c = lane & 15;
      int gc = (c < 8) ? (hd1 + c) : (256 + hd1 + (c - 8));
      ls_rz[w][rl][c] = a1[0][i] + a2[0][i] + a3[0][i] + bih[t1 * 768 + gc] + bhh[t1 * 768 + gc];
      if (c < 8) {
        int gn = 512 + hd1 + c;
        ls_gi[w][rl][c] = a1[1][i] + a3[1][i] + bih[t1 * 768 + gn];
        ls_gh[w][rl][c] = a2[1][i] + bhh[t1 * 768 + gn];
      }
    }
    __syncthreads();
    #pragma unroll
    for (int p = 0; p < 2; ++p) {
      int item = p * 64 + lane;
      int rl = item >> 3, c = item & 7;
      float rv = ls_rz[w][rl][c], zv = ls_rz[w][rl][8 + c];
      float gi = ls_gi[w][rl][c], gh = ls_gh[w][rl][c];
      float r = 1.f / (1.f + expf(-rv));
      float z = 1.f / (1.f + expf(-zv));
      float n = tanhf(gi + r * gh);
      int b = w * 16 + rl;
      int hd = hd1 + c;
      int io = ((s * 2 + t1) * 64 + b) * 256 + hd;
      int oo = (((s + 1) * 2 + t1) * 64 + b) * 256 + hd;
      float hold = hs[io];
      float m = cm[(s * 2 + t1) * 64 + b];
      float hnew = (1.f - z) * n + z * hold;
      float hout = (m > 0.5f) ? hnew : hold;
      hs[oo] = hout;
      u16 xh, xl; split_bf16(hout, xh, xl);
      hhh[oo] = xh; hhl[oo] = xl;
    }
    gridbar(bar, epoch);

    // ---------- phase 2: meta GRU ----------
    f32x4 m1 = (f32x4){0.f, 0.f, 0.f, 0.f};
    f32x4 m2 = (f32x4){0.f, 0.f, 0.f, 0.f};
    #pragma unroll
    for (int ks = 0; ks < 16; ++ks) {
      int tt = ks >> 3;
      int kk = (ks & 7) * 32 + ko;
      const u16* Ah = hhh + (size_t)(((s + 1) * 2 + tt) * 64 + arow) * 256 + kk;
      const u16* Al = hhl + (size_t)(((s + 1) * 2 + tt) * 64 + arow) * 256 + kk;
      short8 xh = *(const short8*)Ah;
      short8 xl = *(const short8*)Al;
      int un = blk * 24 + ks;
      short8 bh = *(const short8*)(w2h + un * 512 + lane * 8);
      short8 bl = *(const short8*)(w2l + un * 512 + lane * 8);
      m1 = mfma16(xh, bh, m1);
      m1 = mfma16(xl, bh, m1);
      m1 = mfma16(xh, bl, m1);
    }
    if (s > 0) {
      #pragma unroll
      for (int ks = 0; ks < 8; ++ks) {
        const u16* Ah = ahi + (size_t)(arow * 30 + (s - 1)) * 256 + ks * 32 + ko;
        const u16* Al = alo + (size_t)(arow * 30 + (s - 1)) * 256 + ks * 32 + ko;
        short8 xh = *(const short8*)Ah;
        short8 xl = *(const short8*)Al;
        int un = blk * 24 + 16 + ks;
        short8 bh = *(const short8*)(w2h + un * 512 + lane * 8);
        short8 bl = *(const short8*)(w2l + un * 512 + lane * 8);
        m2 = mfma16(xh, bh, m2);
        m2 = mfma16(xl, bh, m2);
        m2 = mfma16(xh, bl, m2);
      }
    }
    #pragma unroll
    for (int i = 0; i < 4; ++i) {
      int rl = (lane >> 4) * 4 + i;
      int c = lane & 15;
      if (c < 8) {
        int gc = (c < 4) ? (hd2 + c) : (256 + hd2 + (c - 4));
        ls_rz[w][rl][c] = m1[i] + m2[i] + mbih[gc] + mbhh[gc];
      } else if (c < 12) {
        int gn = 512 + hd2 + (c - 8);
        ls_gi[w][rl][c - 8] = m1[i] + mbih[gn];
        ls_gh[w][rl][c - 8] = m2[i] + mbhh[gn];
      }
    }
    __syncthreads();
    {
      int rl = lane >> 2, c = lane & 3;
      float rv = ls_rz[w][rl][c], zv = ls_rz[w][rl][4 + c];
      float gi = ls_gi[w][rl][c], gh = ls_gh[w][rl][c];
      float r = 1.f / (1.f + expf(-rv));
      float z = 1.f / (1.f + expf(-zv));
      float n = tanhf(gi + r * gh);
      int b = w * 16 + rl;
      int g2 = hd2 + c;
      float hmold = hms[(s * 64 + b) * 256 + g2];
      float hmnew = (1.f - z) * n + z * hmold;
      hms[((s + 1) * 64 + b) * 256 + g2] = hmnew;
      int ar = b * 30 + s;
      u16 xh, xl; split_bf16(hmnew, xh, xl);
      ahi[ar * 256 + g2] = xh;
      alo[ar * 256 + g2] = xl;
    }
    gridbar(bar, epoch);
  }
}

// ---------------- score_new GEMM: [1920,256] x [256,20000] (3-pass split bf16) ----------------
__global__ __launch_bounds__(256) void k_gnew(const u16* __restrict__ ahi, const u16* __restrict__ alo,
                                              const u16* __restrict__ wnh, const u16* __restrict__ wnl,
                                              const float* __restrict__ bnew,
                                              float* __restrict__ out) {
  int bid = blockIdx.x;
  int mb = bid / 157, nb = bid % 157;
  int tid = threadIdx.x, lane = tid & 63, w = tid >> 6;
  int ko = (lane >> 4) * 8;
  f32x4 acc[2][8];
  #pragma unroll
  for (int mi = 0; mi < 2; ++mi)
    #pragma unroll
    for (int nt = 0; nt < 8; ++nt) acc[mi][nt] = (f32x4){0.f, 0.f, 0.f, 0.f};
  #pragma unroll
  for (int ks = 0; ks < 8; ++ks) {
    short8 ah[2], al[2];
    #pragma unroll
    for (int mi = 0; mi < 2; ++mi) {
      int r = mb * 128 + (w * 2 + mi) * 16 + (lane & 15);
      ah[mi] = *(const short8*)(ahi + (size_t)r * 256 + ks * 32 + ko);
      al[mi] = *(const short8*)(alo + (size_t)r * 256 + ks * 32 + ko);
    }
    #pragma unroll
    for (int nt = 0; nt < 8; ++nt) {
      int un = (nb * 8 + nt) * 8 + ks;
      short8 bh = *(const short8*)(wnh + (size_t)un * 512 + lane * 8);
      short8 bl = *(const short8*)(wnl + (size_t)un * 512 + lane * 8);
      #pragma unroll
      for (int mi = 0; mi < 2; ++mi) {
        acc[mi][nt] = mfma16(ah[mi], bh, acc[mi][nt]);
        acc[mi][nt] = mfma16(al[mi], bh, acc[mi][nt]);
        acc[mi][nt] = mfma16(ah[mi], bl, acc[mi][nt]);
      }
    }
  }
  #pragma unroll
  for (int mi = 0; mi < 2; ++mi)
    #pragma unroll
    for (int nt = 0; nt < 8; ++nt) {
      int col = nb * 128 + nt * 16 + (lane & 15);
      if (col < 20000) {
        float bn = bnew[col];
        #pragma unroll
        for (int i = 0; i < 4; ++i) {
          int r = mb * 128 + (w * 2 + mi) * 16 + (lane >> 4) * 4 + i;
          out[(size_t)r * 20000 + col] = acc[mi][nt][i] + bn;
        }
      }
    }
}

// ---------------- sparse copy scores: one wave per (t,b,s) ----------------
__global__ __launch_bounds__(64) void k_copy(const float* __restrict__ hs,
                                             const int* __restrict__ cv,
                                             const float* __restrict__ wc,
                                             const float* __restrict__ bc,
                                             float* __restrict__ out) {
  int u = blockIdx.x;                 // t*1920 + b*30 + s
  int t = u / 1920;
  int rem = u % 1920;
  int b = rem / 30, s = rem % 30;
  int lane = threadIdx.x;
  const float* hp = hs + (size_t)(((s + 1) * 2 + t) * 64 + b) * 256;
  float4 h4 = *(const float4*)(hp + lane * 4);
  int base = u * 20;
  for (int c = 0; c < 20; ++c) {
    int idx = cv[base + c];
    const float* wr = wc + ((size_t)t * 20000 + idx) * 256;
    float4 w4 = *(const float4*)(wr + lane * 4);
    float d = h4.x * w4.x + h4.y * w4.y + h4.z * w4.z + h4.w * w4.w;
    #pragma unroll
    for (int m = 32; m >= 1; m >>= 1) d += __shfl_xor(d, m, 64);
    if (lane == 0)
      out[(size_t)(1 + t) * 38400000 + (size_t)(b * 30 + s) * 20000 + idx] = d + bc[t * 20000 + idx];
  }
}

extern "C" void kernel_launch(void* const* d_in, const int* in_sizes, int n_in,
                              void* d_out, int out_size, void* d_ws, size_t ws_size,
                              hipStream_t stream) {
  const int* iv = (const int*)d_in[1];
  const int* cv = (const int*)d_in[2];
  const float* emb = (const float*)d_in[3];
  const float* Wih = (const float*)d_in[4];
  const float* Whh = (const float*)d_in[5];
  const float* bih = (const float*)d_in[6];
  const float* bhh = (const float*)d_in[7];
  const float* mWih = (const float*)d_in[8];
  const float* mWhh = (const float*)d_in[9];
  const float* mbih = (const float*)d_in[10];
  const float* mbhh = (const float*)d_in[11];
  const float* Wnew = (const float*)d_in[12];
  const float* bnew = (const float*)d_in[13];
  const float* Wcopy = (const float*)d_in[14];
  const float* bcopy = (const float*)d_in[15];
  float* out = (float*)d_out;
  char* ws = (char*)d_ws;

  size_t o = 0;
  auto take = [&](size_t sz) { size_t r = o; o += sz; return r; };
  size_t BAR = take(256);
  size_t CM  = take(15360);
  size_t EBH = take(983040);
  size_t EBL = take(983040);
  size_t HS  = take(4063232);    // fp32 h_seq [31][2][64][256]
  size_t HMS = take(2031616);    // fp32 hm_seq [31][64][256]
  size_t HHH = take(2031616);    // bf16-hi h_seq
  size_t HHL = take(2031616);
  size_t AHI = take(983040);     // bf16-hi hm rows [1920][256]
  size_t ALO = take(983040);
  size_t W1H = take(2621440);
  size_t W1L = take(2621440);
  size_t W2H = take(1572864);
  size_t W2L = take(1572864);
  size_t WNH = take(10289152);
  size_t WNL = take(10289152);
  if (ws_size < o) return;   // insufficient workspace: fail loudly via absmax

  // zero barrier + step-0 state + sparse output region
  hipMemsetAsync(ws + BAR, 0, 256, stream);
  hipMemsetAsync(ws + HS, 0, 131072, stream);
  hipMemsetAsync(ws + HMS, 0, 65536, stream);
  hipMemsetAsync(ws + HHH, 0, 65536, stream);
  hipMemsetAsync(ws + HHL, 0, 65536, stream);
  hipMemsetAsync((char*)d_out + 153600000, 0, 307200000, stream);

  k_pool<<<3840, 128, 0, stream>>>(iv, emb, (u16*)(ws + EBH), (u16*)(ws + EBL), (float*)(ws + CM));
  k_swz<<<3536, 256, 0, stream>>>(Wih, Whh, mWih, mWhh, Wnew,
                                  (u16*)(ws + W1H), (u16*)(ws + W1L),
                                  (u16*)(ws + W2H), (u16*)(ws + W2L),
                                  (u16*)(ws + WNH), (u16*)(ws + WNL));
  k_rnn<<<NB_, 256, 0, stream>>>((const u16*)(ws + EBH), (const u16*)(ws + EBL),
                                 (const u16*)(ws + W1H), (const u16*)(ws + W1L),
                                 (const u16*)(ws + W2H), (const u16*)(ws + W2L),
                                 bih, bhh, mbih, mbhh, (const float*)(ws + CM),
                                 (float*)(ws + HS), (float*)(ws + HMS),
                                 (u16*)(ws + HHH), (u16*)(ws + HHL),
                                 (u16*)(ws + AHI), (u16*)(ws + ALO),
                                 (int*)(ws + BAR));
  k_gnew<<<2355, 256, 0, stream>>>((const u16*)(ws + AHI), (const u16*)(ws + ALO),
                                   (const u16*)(ws + WNH), (const u16*)(ws + WNL),
                                   bnew, out);
  k_copy<<<3840, 64, 0, stream>>>((const float*)(ws + HS), cv, Wcopy, bcopy, out);
}

// Round 2
// 1274.063 us; speedup vs baseline: 1.1753x; 1.1753x over previous
//
#include <hip/hip_runtime.h>

typedef unsigned short u16;
typedef unsigned int u32;
typedef unsigned long long u64;
typedef __attribute__((ext_vector_type(8))) short short8;
typedef __attribute__((ext_vector_type(4))) float f32x4;

#define NB_ 64

static __device__ __forceinline__ f32x4 mfma16(short8 a, short8 b, f32x4 c) {
  return __builtin_amdgcn_mfma_f32_16x16x32_bf16(a, b, c, 0, 0, 0);
}

// split fp32 -> bf16 hi + bf16 lo  (x ~= hi + lo, residual ~2^-17 * |x|)
static __device__ __forceinline__ void split_bf16(float x, u16& hi, u16& lo) {
  unsigned u = __float_as_uint(x);
  unsigned r = (u + 0x7fffu + ((u >> 16) & 1u)) >> 16;
  hi = (u16)r;
  float fh = __uint_as_float(r << 16);
  float xl = x - fh;
  unsigned ul = __float_as_uint(xl);
  unsigned rl2 = (ul + 0x7fffu + ((ul >> 16) & 1u)) >> 16;
  lo = (u16)rl2;
}

// coherent (L2-bypassing) cross-block ops: relaxed agent-scope atomics
static __device__ __forceinline__ void astore(u32* p, u32 v) {
  __hip_atomic_store(p, v, __ATOMIC_RELAXED, __HIP_MEMORY_SCOPE_AGENT);
}
// load 8 packed elements (32B) -> hi-frag + lo-frag
static __device__ __forceinline__ void aload8(const u32* p, short8& h, short8& l) {
  u64 d[4];
  #pragma unroll
  for (int j = 0; j < 4; ++j)
    d[j] = __hip_atomic_load((const u64*)p + j, __ATOMIC_RELAXED, __HIP_MEMORY_SCOPE_AGENT);
  #pragma unroll
  for (int j = 0; j < 4; ++j) {
    u32 lo = (u32)d[j], hi = (u32)(d[j] >> 32);
    h[2 * j]     = (short)(lo & 0xffffu);  l[2 * j]     = (short)(lo >> 16);
    h[2 * j + 1] = (short)(hi & 0xffffu);  l[2 * j + 1] = (short)(hi >> 16);
  }
}

// ---------------- pooling: emb gather + mean over valid items ----------------
__global__ __launch_bounds__(128) void k_pool(const int* __restrict__ iv,
                                              const float* __restrict__ emb,
                                              u16* __restrict__ ebh, u16* __restrict__ ebl,
                                              float* __restrict__ cm) {
  int u = blockIdx.x;             // u = (s*2+t)*64+b
  int s = u >> 7;
  int t = (u >> 6) & 1;
  int b = u & 63;
  int d = threadIdx.x;
  const int ibase = ((t * 64 + b) * 30 + s) * 12;
  float sum = 0.f;
  int cnt = 0;
  for (int k = 0; k < 12; ++k) {
    int idx = iv[ibase + k];
    if (idx > 0) { cnt++; sum += emb[(size_t)idx * 128 + d]; }
  }
  float den = (cnt > 0) ? (float)cnt : 1.f;
  float v = sum / den;
  u16 hi, lo; split_bf16(v, hi, lo);
  ebh[(size_t)u * 128 + d] = hi;
  ebl[(size_t)u * 128 + d] = lo;
  if (d == 0) cm[u] = (cnt > 0) ? 1.f : 0.f;
}

// ---------------- weight swizzle into MFMA B-fragment layout ----------------
// B-frag (16x16x32): lane l holds B[k=(l>>4)*8+j][n=l&15], j=0..7
__global__ __launch_bounds__(256) void k_swz(const float* __restrict__ Wih,
                                             const float* __restrict__ Whh,
                                             const float* __restrict__ mWih,
                                             const float* __restrict__ mWhh,
                                             const float* __restrict__ Wnew,
                                             u16* __restrict__ w1h, u16* __restrict__ w1l,
                                             u16* __restrict__ w2h, u16* __restrict__ w2l,
                                             u16* __restrict__ wnh, u16* __restrict__ wnl) {
  int gu = blockIdx.x * 4 + (threadIdx.x >> 6);
  int lane = threadIdx.x & 63;
  int ko = (lane >> 4) * 8;
  int cl = lane & 15;
  float src[8];
  if (gu < 2560) {
    int blk = gu / 40, r = gu % 40, ksIdx = r >> 1, nt = r & 1;
    int t = blk >> 5, hd0 = (blk & 31) * 8;
    int c = nt * 16 + cl;
    if (c < 24) {
      int gc = (c < 8) ? (hd0 + c) : (c < 16) ? (256 + hd0 + (c - 8)) : (512 + hd0 + (c - 16));
      const float* wrow; int kk;
      if (ksIdx < 8)       { wrow = Wih + (size_t)(t * 768 + gc) * 384 + 128; kk = ksIdx * 32 + ko; }
      else if (ksIdx < 16) { wrow = Whh + (size_t)(t * 768 + gc) * 256;       kk = (ksIdx - 8) * 32 + ko; }
      else                 { wrow = Wih + (size_t)(t * 768 + gc) * 384;       kk = (ksIdx - 16) * 32 + ko; }
      #pragma unroll
      for (int j = 0; j < 8; ++j) src[j] = wrow[kk + j];
    } else {
      #pragma unroll
      for (int j = 0; j < 8; ++j) src[j] = 0.f;
    }
    int off = gu * 512 + lane * 8;
    #pragma unroll
    for (int j = 0; j < 8; ++j) { u16 h, l; split_bf16(src[j], h, l); w1h[off + j] = h; w1l[off + j] = l; }
  } else if (gu < 4096) {
    int g2 = gu - 2560;
    int blk = g2 / 24, ksIdx = g2 % 24;
    int hd0 = blk * 4;
    int c = cl;
    if (c < 12) {
      int gc = (c < 4) ? (hd0 + c) : (c < 8) ? (256 + hd0 + (c - 4)) : (512 + hd0 + (c - 8));
      if (ksIdx < 16) {
        int kk = ksIdx * 32 + ko;
        #pragma unroll
        for (int j = 0; j < 8; ++j) src[j] = mWih[(size_t)gc * 512 + kk + j];
      } else {
        int kk = (ksIdx - 16) * 32 + ko;
        #pragma unroll
        for (int j = 0; j < 8; ++j) src[j] = mWhh[(size_t)gc * 256 + kk + j];
      }
    } else {
      #pragma unroll
      for (int j = 0; j < 8; ++j) src[j] = 0.f;
    }
    int off = g2 * 512 + lane * 8;
    #pragma unroll
    for (int j = 0; j < 8; ++j) { u16 h, l; split_bf16(src[j], h, l); w2h[off + j] = h; w2l[off + j] = l; }
  } else if (gu < 14144) {
    int g3 = gu - 4096;
    int gnt = g3 >> 3, ks = g3 & 7;
    int col = gnt * 16 + cl;
    if (col < 20000) {
      int kk = ks * 32 + ko;
      #pragma unroll
      for (int j = 0; j < 8; ++j) src[j] = Wnew[(size_t)col * 256 + kk + j];
    } else {
      #pragma unroll
      for (int j = 0; j < 8; ++j) src[j] = 0.f;
    }
    int off = g3 * 512 + lane * 8;
    #pragma unroll
    for (int j = 0; j < 8; ++j) { u16 h, l; split_bf16(src[j], h, l); wnh[off + j] = h; wnl[off + j] = l; }
  }
}

// ---------------- persistent GRU recurrence ----------------
// Barrier with ZERO cache-maintenance ops: all cross-block data moves through
// L2-bypassing relaxed agent atomics, so no acquire-invalidate / release-wbl2
// is needed and per-block weight slices stay L2-resident across all 30 steps.
static __device__ __forceinline__ void gridbar(int* bar, int& epoch) {
  __syncthreads();              // drains vmcnt for ALL waves of the block
  ++epoch;
  if (threadIdx.x == 0) {
    asm volatile("s_waitcnt vmcnt(0)" ::: "memory");
    __hip_atomic_fetch_add(bar, 1, __ATOMIC_RELAXED, __HIP_MEMORY_SCOPE_AGENT);
    while (__hip_atomic_load(bar, __ATOMIC_RELAXED, __HIP_MEMORY_SCOPE_AGENT) < epoch * NB_)
      __builtin_amdgcn_s_sleep(2);
  }
  __syncthreads();
}

__global__ __launch_bounds__(256) void k_rnn(
    const u16* __restrict__ ebh, const u16* __restrict__ ebl,
    const u16* __restrict__ w1h, const u16* __restrict__ w1l,
    const u16* __restrict__ w2h, const u16* __restrict__ w2l,
    const float* __restrict__ bih, const float* __restrict__ bhh,
    const float* __restrict__ mbih, const float* __restrict__ mbhh,
    const float* __restrict__ cm,
    float* __restrict__ hs, float* __restrict__ hms,
    u32* __restrict__ hpk,       // packed (hi|lo<<16) task-h   [31][2][64][256]
    u32* __restrict__ apk,       // packed (hi|lo<<16) meta-h   [1920][256] (b*30+s)
    int* bar) {
  const int blk = blockIdx.x;
  const int tid = threadIdx.x;
  const int lane = tid & 63;
  const int w = tid >> 6;
  const int t1 = blk >> 5;
  const int hd1 = (blk & 31) * 8;
  const int hd2 = blk * 4;
  const int arow = w * 16 + (lane & 15);
  const int ko = (lane >> 4) * 8;
  int epoch = 0;

  __shared__ float ls_rz[4][16][16];
  __shared__ float ls_gi[4][16][8];
  __shared__ float ls_gh[4][16][8];

  for (int s = 0; s < 30; ++s) {
    // ---------- phase 1: task GRUs ----------
    f32x4 a1[2], a2[2], a3[2];
    #pragma unroll
    for (int i = 0; i < 2; ++i) {
      a1[i] = (f32x4){0.f, 0.f, 0.f, 0.f};
      a2[i] = (f32x4){0.f, 0.f, 0.f, 0.f};
      a3[i] = (f32x4){0.f, 0.f, 0.f, 0.f};
    }
    if (s > 0) {
      // G1: h_meta @ WihH
      const u32* Ap = apk + (size_t)(arow * 30 + (s - 1)) * 256;
      #pragma unroll
      for (int ks = 0; ks < 8; ++ks) {
        short8 xh, xl;
        aload8(Ap + ks * 32 + ko, xh, xl);
        #pragma unroll
        for (int nt = 0; nt < 2; ++nt) {
          int un = (blk * 20 + ks) * 2 + nt;
          short8 bh = *(const short8*)(w1h + un * 512 + lane * 8);
          short8 bl = *(const short8*)(w1l + un * 512 + lane * 8);
          a1[nt] = mfma16(xh, bh, a1[nt]);
          a1[nt] = mfma16(xl, bh, a1[nt]);
          a1[nt] = mfma16(xh, bl, a1[nt]);
        }
      }
      // G2: h_task @ Whh
      const u32* Hp = hpk + (size_t)((s * 2 + t1) * 64 + arow) * 256;
      #pragma unroll
      for (int ks = 0; ks < 8; ++ks) {
        short8 xh, xl;
        aload8(Hp + ks * 32 + ko, xh, xl);
        #pragma unroll
        for (int nt = 0; nt < 2; ++nt) {
          int un = (blk * 20 + 8 + ks) * 2 + nt;
          short8 bh = *(const short8*)(w1h + un * 512 + lane * 8);
          short8 bl = *(const short8*)(w1l + un * 512 + lane * 8);
          a2[nt] = mfma16(xh, bh, a2[nt]);
          a2[nt] = mfma16(xl, bh, a2[nt]);
          a2[nt] = mfma16(xh, bl, a2[nt]);
        }
      }
    }
    {
      // G3: x @ WihX (K=128) — cached normal loads (written before kernel)
      const u16* Xh = ebh + (size_t)((s * 2 + t1) * 64 + arow) * 128;
      const u16* Xl = ebl + (size_t)((s * 2 + t1) * 64 + arow) * 128;
      #pragma unroll
      for (int ks = 0; ks < 4; ++ks) {
        short8 xh = *(const short8*)(Xh + ks * 32 + ko);
        short8 xl = *(const short8*)(Xl + ks * 32 + ko);
        #pragma unroll
        for (int nt = 0; nt < 2; ++nt) {
          int un = (blk * 20 + 16 + ks) * 2 + nt;
          short8 bh = *(const short8*)(w1h + un * 512 + lane * 8);
          short8 bl = *(const short8*)(w1l + un * 512 + lane * 8);
          a3[nt] = mfma16(xh, bh, a3[nt]);
          a3[nt] = mfma16(xl, bh, a3[nt]);
          a3[nt] = mfma16(xh, bl, a3[nt]);
        }
      }
    }
    // gate pre-activations -> LDS (C layout: row=(l>>4)*4+i, col=l&15)
    #pragma unroll
    for (int i = 0; i < 4; ++i) {
      int rl = (lane >> 4) * 4 + i;
      int c = lane & 15;
      int gc = (c < 8) ? (hd1 + c) : (256 + hd1 + (c - 8));
      ls_rz[w][rl][c] = a1[0][i] + a2[0][i] + a3[0][i] + bih[t1 * 768 + gc] + bhh[t1 * 768 + gc];
      if (c < 8) {
        int gn = 512 + hd1 + c;
        ls_gi[w][rl][c] = a1[1][i] + a3[1][i] + bih[t1 * 768 + gn];
        ls_gh[w][rl][c] = a2[1][i] + bhh[t1 * 768 + gn];
      }
    }
    __syncthreads();
    #pragma unroll
    for (int p = 0; p < 2; ++p) {
      int item = p * 64 + lane;
      int rl = item >> 3, c = item & 7;
      float rv = ls_rz[w][rl][c], zv = ls_rz[w][rl][8 + c];
      float gi = ls_gi[w][rl][c], gh = ls_gh[w][rl][c];
      float r = 1.f / (1.f + expf(-rv));
      float z = 1.f / (1.f + expf(-zv));
      float n = tanhf(gi + r * gh);
      int b = w * 16 + rl;
      int hd = hd1 + c;
      int io = ((s * 2 + t1) * 64 + b) * 256 + hd;
      int oo = (((s + 1) * 2 + t1) * 64 + b) * 256 + hd;
      float hold = hs[io];
      float m = cm[(s * 2 + t1) * 64 + b];
      float hnew = (1.f - z) * n + z * hold;
      float hout = (m > 0.5f) ? hnew : hold;
      hs[oo] = hout;
      u16 xh, xl; split_bf16(hout, xh, xl);
      astore(hpk + oo, (u32)xh | ((u32)xl << 16));
    }
    gridbar(bar, epoch);

    // ---------- phase 2: meta GRU ----------
    f32x4 m1 = (f32x4){0.f, 0.f, 0.f, 0.f};
    f32x4 m2 = (f32x4){0.f, 0.f, 0.f, 0.f};
    #pragma unroll
    for (int ks = 0; ks < 16; ++ks) {
      int tt = ks >> 3;
      int kk = (ks & 7) * 32 + ko;
      short8 xh, xl;
      aload8(hpk + (size_t)(((s + 1) * 2 + tt) * 64 + arow) * 256 + kk, xh, xl);
      int un = blk * 24 + ks;
      short8 bh = *(const short8*)(w2h + un * 512 + lane * 8);
      short8 bl = *(const short8*)(w2l + un * 512 + lane * 8);
      m1 = mfma16(xh, bh, m1);
      m1 = mfma16(xl, bh, m1);
      m1 = mfma16(xh, bl, m1);
    }
    if (s > 0) {
      #pragma unroll
      for (int ks = 0; ks < 8; ++ks) {
        short8 xh, xl;
        aload8(apk + (size_t)(arow * 30 + (s - 1)) * 256 + ks * 32 + ko, xh, xl);
        int un = blk * 24 + 16 + ks;
        short8 bh = *(const short8*)(w2h + un * 512 + lane * 8);
        short8 bl = *(const short8*)(w2l + un * 512 + lane * 8);
        m2 = mfma16(xh, bh, m2);
        m2 = mfma16(xl, bh, m2);
        m2 = mfma16(xh, bl, m2);
      }
    }
    #pragma unroll
    for (int i = 0; i < 4; ++i) {
      int rl = (lane >> 4) * 4 + i;
      int c = lane & 15;
      if (c < 8) {
        int gc = (c < 4) ? (hd2 + c) : (256 + hd2 + (c - 4));
        ls_rz[w][rl][c] = m1[i] + m2[i] + mbih[gc] + mbhh[gc];
      } else if (c < 12) {
        int gn = 512 + hd2 + (c - 8);
        ls_gi[w][rl][c - 8] = m1[i] + mbih[gn];
        ls_gh[w][rl][c - 8] = m2[i] + mbhh[gn];
      }
    }
    __syncthreads();
    {
      int rl = lane >> 2, c = lane & 3;
      float rv = ls_rz[w][rl][c], zv = ls_rz[w][rl][4 + c];
      float gi = ls_gi[w][rl][c], gh = ls_gh[w][rl][c];
      float r = 1.f / (1.f + expf(-rv));
      float z = 1.f / (1.f + expf(-zv));
      float n = tanhf(gi + r * gh);
      int b = w * 16 + rl;
      int g2 = hd2 + c;
      float hmold = hms[(s * 64 + b) * 256 + g2];
      float hmnew = (1.f - z) * n + z * hmold;
      hms[((s + 1) * 64 + b) * 256 + g2] = hmnew;
      int ar = b * 30 + s;
      u16 xh, xl; split_bf16(hmnew, xh, xl);
      astore(apk + ar * 256 + g2, (u32)xh | ((u32)xl << 16));
    }
    gridbar(bar, epoch);
  }
}

// ---------------- score_new GEMM: [1920,256] x [256,20000] (3-pass split bf16) ----------------
__global__ __launch_bounds__(256) void k_gnew(const u32* __restrict__ apk,
                                              const u16* __restrict__ wnh, const u16* __restrict__ wnl,
                                              const float* __restrict__ bnew,
                                              float* __restrict__ out) {
  int bid = blockIdx.x;
  int mb = bid / 157, nb = bid % 157;
  int tid = threadIdx.x, lane = tid & 63, w = tid >> 6;
  int ko = (lane >> 4) * 8;
  f32x4 acc[2][8];
  #pragma unroll
  for (int mi = 0; mi < 2; ++mi)
    #pragma unroll
    for (int nt = 0; nt < 8; ++nt) acc[mi][nt] = (f32x4){0.f, 0.f, 0.f, 0.f};
  #pragma unroll
  for (int ks = 0; ks < 8; ++ks) {
    short8 ah[2], al[2];
    #pragma unroll
    for (int mi = 0; mi < 2; ++mi) {
      int r = mb * 128 + (w * 2 + mi) * 16 + (lane & 15);
      const u32* p = apk + (size_t)r * 256 + ks * 32 + ko;
      uint4 w0 = *(const uint4*)p;
      uint4 w1v = *(const uint4*)(p + 4);
      u32 wb[8] = {w0.x, w0.y, w0.z, w0.w, w1v.x, w1v.y, w1v.z, w1v.w};
      #pragma unroll
      for (int j = 0; j < 8; ++j) {
        ah[mi][j] = (short)(wb[j] & 0xffffu);
        al[mi][j] = (short)(wb[j] >> 16);
      }
    }
    #pragma unroll
    for (int nt = 0; nt < 8; ++nt) {
      int un = (nb * 8 + nt) * 8 + ks;
      short8 bh = *(const short8*)(wnh + (size_t)un * 512 + lane * 8);
      short8 bl = *(const short8*)(wnl + (size_t)un * 512 + lane * 8);
      #pragma unroll
      for (int mi = 0; mi < 2; ++mi) {
        acc[mi][nt] = mfma16(ah[mi], bh, acc[mi][nt]);
        acc[mi][nt] = mfma16(al[mi], bh, acc[mi][nt]);
        acc[mi][nt] = mfma16(ah[mi], bl, acc[mi][nt]);
      }
    }
  }
  #pragma unroll
  for (int mi = 0; mi < 2; ++mi)
    #pragma unroll
    for (int nt = 0; nt < 8; ++nt) {
      int col = nb * 128 + nt * 16 + (lane & 15);
      if (col < 20000) {
        float bn = bnew[col];
        #pragma unroll
        for (int i = 0; i < 4; ++i) {
          int r = mb * 128 + (w * 2 + mi) * 16 + (lane >> 4) * 4 + i;
          out[(size_t)r * 20000 + col] = acc[mi][nt][i] + bn;
        }
      }
    }
}

// ---------------- sparse copy scores: one wave per (t,b,s) ----------------
__global__ __launch_bounds__(64) void k_copy(const float* __restrict__ hs,
                                             const int* __restrict__ cv,
                                             const float* __restrict__ wc,
                                             const float* __restrict__ bc,
                                             float* __restrict__ out) {
  int u = blockIdx.x;                 // t*1920 + b*30 + s
  int t = u / 1920;
  int rem = u % 1920;
  int b = rem / 30, s = rem % 30;
  int lane = threadIdx.x;
  const float* hp = hs + (size_t)(((s + 1) * 2 + t) * 64 + b) * 256;
  float4 h4 = *(const float4*)(hp + lane * 4);
  int base = u * 20;
  for (int c = 0; c < 20; ++c) {
    int idx = cv[base + c];
    const float* wr = wc + ((size_t)t * 20000 + idx) * 256;
    float4 w4 = *(const float4*)(wr + lane * 4);
    float d = h4.x * w4.x + h4.y * w4.y + h4.z * w4.z + h4.w * w4.w;
    #pragma unroll
    for (int m = 32; m >= 1; m >>= 1) d += __shfl_xor(d, m, 64);
    if (lane == 0)
      out[(size_t)(1 + t) * 38400000 + (size_t)(b * 30 + s) * 20000 + idx] = d + bc[t * 20000 + idx];
  }
}

extern "C" void kernel_launch(void* const* d_in, const int* in_sizes, int n_in,
                              void* d_out, int out_size, void* d_ws, size_t ws_size,
                              hipStream_t stream) {
  const int* iv = (const int*)d_in[1];
  const int* cv = (const int*)d_in[2];
  const float* emb = (const float*)d_in[3];
  const float* Wih = (const float*)d_in[4];
  const float* Whh = (const float*)d_in[5];
  const float* bih = (const float*)d_in[6];
  const float* bhh = (const float*)d_in[7];
  const float* mWih = (const float*)d_in[8];
  const float* mWhh = (const float*)d_in[9];
  const float* mbih = (const float*)d_in[10];
  const float* mbhh = (const float*)d_in[11];
  const float* Wnew = (const float*)d_in[12];
  const float* bnew = (const float*)d_in[13];
  const float* Wcopy = (const float*)d_in[14];
  const float* bcopy = (const float*)d_in[15];
  float* out = (float*)d_out;
  char* ws = (char*)d_ws;

  size_t o = 0;
  auto take = [&](size_t sz) { size_t r = o; o += sz; return r; };
  size_t BAR = take(256);
  size_t CM  = take(15360);
  size_t EBH = take(983040);
  size_t EBL = take(983040);
  size_t HS  = take(4063232);    // fp32 h_seq [31][2][64][256]
  size_t HMS = take(2031616);    // fp32 hm_seq [31][64][256]
  size_t HPK = take(4063232);    // packed bf16 hi|lo task-h [31][2][64][256] u32
  size_t APK = take(1966080);    // packed bf16 hi|lo meta-h [1920][256] u32
  size_t W1H = take(2621440);
  size_t W1L = take(2621440);
  size_t W2H = take(1572864);
  size_t W2L = take(1572864);
  size_t WNH = take(10289152);
  size_t WNL = take(10289152);
  if (ws_size < o) return;   // insufficient workspace: fail loudly via absmax

  // zero barrier + step-0 state + sparse output region
  hipMemsetAsync(ws + BAR, 0, 256, stream);
  hipMemsetAsync(ws + HS, 0, 131072, stream);
  hipMemsetAsync(ws + HMS, 0, 65536, stream);
  hipMemsetAsync(ws + HPK, 0, 131072, stream);
  hipMemsetAsync((char*)d_out + 153600000, 0, 307200000, stream);

  k_pool<<<3840, 128, 0, stream>>>(iv, emb, (u16*)(ws + EBH), (u16*)(ws + EBL), (float*)(ws + CM));
  k_swz<<<3536, 256, 0, stream>>>(Wih, Whh, mWih, mWhh, Wnew,
                                  (u16*)(ws + W1H), (u16*)(ws + W1L),
                                  (u16*)(ws + W2H), (u16*)(ws + W2L),
                                  (u16*)(ws + WNH), (u16*)(ws + WNL));
  k_rnn<<<NB_, 256, 0, stream>>>((const u16*)(ws + EBH), (const u16*)(ws + EBL),
                                 (const u16*)(ws + W1H), (const u16*)(ws + W1L),
                                 (const u16*)(ws + W2H), (const u16*)(ws + W2L),
                                 bih, bhh, mbih, mbhh, (const float*)(ws + CM),
                                 (float*)(ws + HS), (float*)(ws + HMS),
                                 (u32*)(ws + HPK), (u32*)(ws + APK),
                                 (int*)(ws + BAR));
  k_gnew<<<2355, 256, 0, stream>>>((const u32*)(ws + APK),
                                   (const u16*)(ws + WNH), (const u16*)(ws + WNL),
                                   bnew, out);
  k_copy<<<3840, 64, 0, stream>>>((const float*)(ws + HS), cv, Wcopy, bcopy, out);
}

// Round 3
// 869.915 us; speedup vs baseline: 1.7214x; 1.4646x over previous
//
#include <hip/hip_runtime.h>

typedef unsigned short u16;
typedef unsigned int u32;
typedef unsigned long long u64;
typedef __attribute__((ext_vector_type(8))) short short8;
typedef __attribute__((ext_vector_type(4))) float f32x4;

#define NB_ 64

static __device__ __forceinline__ f32x4 mfma16(short8 a, short8 b, f32x4 c) {
  return __builtin_amdgcn_mfma_f32_16x16x32_bf16(a, b, c, 0, 0, 0);
}

// split fp32 -> bf16 hi + bf16 lo  (x ~= hi + lo, residual ~2^-17 * |x|)
static __device__ __forceinline__ void split_bf16(float x, u16& hi, u16& lo) {
  unsigned u = __float_as_uint(x);
  unsigned r = (u + 0x7fffu + ((u >> 16) & 1u)) >> 16;
  hi = (u16)r;
  float fh = __uint_as_float(r << 16);
  float xl = x - fh;
  unsigned ul = __float_as_uint(xl);
  unsigned rl2 = (ul + 0x7fffu + ((ul >> 16) & 1u)) >> 16;
  lo = (u16)rl2;
}

// coherent cross-block ops: relaxed agent-scope atomics (proven correct r1/r2)
static __device__ __forceinline__ void astore(u32* p, u32 v) {
  __hip_atomic_store(p, v, __ATOMIC_RELAXED, __HIP_MEMORY_SCOPE_AGENT);
}
static __device__ __forceinline__ void aload8(const u32* p, short8& h, short8& l) {
  u64 d[4];
  #pragma unroll
  for (int j = 0; j < 4; ++j)
    d[j] = __hip_atomic_load((const u64*)p + j, __ATOMIC_RELAXED, __HIP_MEMORY_SCOPE_AGENT);
  #pragma unroll
  for (int j = 0; j < 4; ++j) {
    u32 lo = (u32)d[j], hi = (u32)(d[j] >> 32);
    h[2 * j]     = (short)(lo & 0xffffu);  l[2 * j]     = (short)(lo >> 16);
    h[2 * j + 1] = (short)(hi & 0xffffu);  l[2 * j + 1] = (short)(hi >> 16);
  }
}

// ---------------- pooling: emb gather + mean over valid items ----------------
__global__ __launch_bounds__(128) void k_pool(const int* __restrict__ iv,
                                              const float* __restrict__ emb,
                                              u16* __restrict__ ebh, u16* __restrict__ ebl,
                                              float* __restrict__ cm) {
  int u = blockIdx.x;             // u = (s*2+t)*64+b
  int s = u >> 7;
  int t = (u >> 6) & 1;
  int b = u & 63;
  int d = threadIdx.x;
  const int ibase = ((t * 64 + b) * 30 + s) * 12;
  float sum = 0.f;
  int cnt = 0;
  for (int k = 0; k < 12; ++k) {
    int idx = iv[ibase + k];
    if (idx > 0) { cnt++; sum += emb[(size_t)idx * 128 + d]; }
  }
  float den = (cnt > 0) ? (float)cnt : 1.f;
  float v = sum / den;
  u16 hi, lo; split_bf16(v, hi, lo);
  ebh[(size_t)u * 128 + d] = hi;
  ebl[(size_t)u * 128 + d] = lo;
  if (d == 0) cm[u] = (cnt > 0) ? 1.f : 0.f;
}

// ---------------- weight swizzle into MFMA B-fragment layout ----------------
// B-frag (16x16x32): lane l holds B[k=(l>>4)*8+j][n=l&15], j=0..7
// w1: 64 blk * 20 ks * 2 nt; ks 0..7 WihH(K=256), 8..15 Whh(K=256), 16..19 WihX(K=128)
// w2: 64 blk * 24 ks; ks 0..7 mWih OWN task (t1=blk>>5), 8..15 mWih other task, 16..23 mWhh
__global__ __launch_bounds__(256) void k_swz(const float* __restrict__ Wih,
                                             const float* __restrict__ Whh,
                                             const float* __restrict__ mWih,
                                             const float* __restrict__ mWhh,
                                             const float* __restrict__ Wnew,
                                             u16* __restrict__ w1h, u16* __restrict__ w1l,
                                             u16* __restrict__ w2h, u16* __restrict__ w2l,
                                             u16* __restrict__ wnh, u16* __restrict__ wnl) {
  int gu = blockIdx.x * 4 + (threadIdx.x >> 6);
  int lane = threadIdx.x & 63;
  int ko = (lane >> 4) * 8;
  int cl = lane & 15;
  float src[8];
  if (gu < 2560) {
    int blk = gu / 40, r = gu % 40, ksIdx = r >> 1, nt = r & 1;
    int t = blk >> 5, hd0 = (blk & 31) * 8;
    int c = nt * 16 + cl;
    if (c < 24) {
      int gc = (c < 8) ? (hd0 + c) : (c < 16) ? (256 + hd0 + (c - 8)) : (512 + hd0 + (c - 16));
      const float* wrow; int kk;
      if (ksIdx < 8)       { wrow = Wih + (size_t)(t * 768 + gc) * 384 + 128; kk = ksIdx * 32 + ko; }
      else if (ksIdx < 16) { wrow = Whh + (size_t)(t * 768 + gc) * 256;       kk = (ksIdx - 8) * 32 + ko; }
      else                 { wrow = Wih + (size_t)(t * 768 + gc) * 384;       kk = (ksIdx - 16) * 32 + ko; }
      #pragma unroll
      for (int j = 0; j < 8; ++j) src[j] = wrow[kk + j];
    } else {
      #pragma unroll
      for (int j = 0; j < 8; ++j) src[j] = 0.f;
    }
    int off = gu * 512 + lane * 8;
    #pragma unroll
    for (int j = 0; j < 8; ++j) { u16 h, l; split_bf16(src[j], h, l); w1h[off + j] = h; w1l[off + j] = l; }
  } else if (gu < 4096) {
    int g2 = gu - 2560;
    int blk = g2 / 24, ksIdx = g2 % 24;
    int t1 = blk >> 5;
    int hd0 = blk * 4;
    int c = cl;
    if (c < 12) {
      int gc = (c < 4) ? (hd0 + c) : (c < 8) ? (256 + hd0 + (c - 4)) : (512 + hd0 + (c - 8));
      if (ksIdx < 16) {
        int chunk = (ksIdx < 8) ? (t1 * 8 + ksIdx) : ((1 - t1) * 8 + (ksIdx - 8));
        int kk = chunk * 32 + ko;
        #pragma unroll
        for (int j = 0; j < 8; ++j) src[j] = mWih[(size_t)gc * 512 + kk + j];
      } else {
        int kk = (ksIdx - 16) * 32 + ko;
        #pragma unroll
        for (int j = 0; j < 8; ++j) src[j] = mWhh[(size_t)gc * 256 + kk + j];
      }
    } else {
      #pragma unroll
      for (int j = 0; j < 8; ++j) src[j] = 0.f;
    }
    int off = g2 * 512 + lane * 8;
    #pragma unroll
    for (int j = 0; j < 8; ++j) { u16 h, l; split_bf16(src[j], h, l); w2h[off + j] = h; w2l[off + j] = l; }
  } else if (gu < 14144) {
    int g3 = gu - 4096;
    int gnt = g3 >> 3, ks = g3 & 7;
    int col = gnt * 16 + cl;
    if (col < 20000) {
      int kk = ks * 32 + ko;
      #pragma unroll
      for (int j = 0; j < 8; ++j) src[j] = Wnew[(size_t)col * 256 + kk + j];
    } else {
      #pragma unroll
      for (int j = 0; j < 8; ++j) src[j] = 0.f;
    }
    int off = g3 * 512 + lane * 8;
    #pragma unroll
    for (int j = 0; j < 8; ++j) { u16 h, l; split_bf16(src[j], h, l); wnh[off + j] = h; wnl[off + j] = l; }
  }
}

// ---------------- gi_x precompute: gi_x = x @ WihX^T (+bias folds) ----------------
// layout: gix[blk][s][row 0..63][32]: cols 0..15 = r,z (+bih+bhh), 16..23 = n (+bih)
__global__ __launch_bounds__(256) void k_gix(const u16* __restrict__ ebh, const u16* __restrict__ ebl,
                                             const u16* __restrict__ w1h, const u16* __restrict__ w1l,
                                             const float* __restrict__ bih, const float* __restrict__ bhh,
                                             float* __restrict__ gix) {
  int blk = blockIdx.x;
  int t1 = blk >> 5, hd1 = (blk & 31) * 8;
  int tid = threadIdx.x, lane = tid & 63, w = tid >> 6;
  int arow = w * 16 + (lane & 15);
  int ko = (lane >> 4) * 8;
  __shared__ u16 lwh[4096], lwl[4096];
  {
    const uint4* sh = (const uint4*)(w1h + ((size_t)blk * 40 + 32) * 512);
    const uint4* sl = (const uint4*)(w1l + ((size_t)blk * 40 + 32) * 512);
    uint4* dh = (uint4*)lwh; uint4* dl = (uint4*)lwl;
    for (int i = tid; i < 512; i += 256) { dh[i] = sh[i]; dl[i] = sl[i]; }
  }
  int c = lane & 15;
  float brz, bn = 0.f;
  {
    int gc = (c < 8) ? (hd1 + c) : (256 + hd1 + (c - 8));
    brz = bih[t1 * 768 + gc] + bhh[t1 * 768 + gc];
    if (c < 8) bn = bih[t1 * 768 + 512 + hd1 + c];
  }
  __syncthreads();
  for (int s = 0; s < 30; ++s) {
    f32x4 a3[2];
    a3[0] = (f32x4){0.f, 0.f, 0.f, 0.f};
    a3[1] = (f32x4){0.f, 0.f, 0.f, 0.f};
    const u16* Xh = ebh + (size_t)((s * 2 + t1) * 64 + arow) * 128;
    const u16* Xl = ebl + (size_t)((s * 2 + t1) * 64 + arow) * 128;
    #pragma unroll
    for (int k = 0; k < 4; ++k) {
      short8 xh = *(const short8*)(Xh + k * 32 + ko);
      short8 xl = *(const short8*)(Xl + k * 32 + ko);
      #pragma unroll
      for (int nt = 0; nt < 2; ++nt) {
        short8 bh = *(const short8*)(lwh + (k * 2 + nt) * 512 + lane * 8);
        short8 bl = *(const short8*)(lwl + (k * 2 + nt) * 512 + lane * 8);
        a3[nt] = mfma16(xh, bh, a3[nt]);
        a3[nt] = mfma16(xl, bh, a3[nt]);
        a3[nt] = mfma16(xh, bl, a3[nt]);
      }
    }
    float* grow = gix + (size_t)(blk * 30 + s) * 64 * 32;
    #pragma unroll
    for (int i = 0; i < 4; ++i) {
      int r = w * 16 + (lane >> 4) * 4 + i;
      grow[r * 32 + c] = a3[0][i] + brz;
      if (c < 8) grow[r * 32 + 16 + c] = a3[1][i] + bn;
    }
  }
}

// ---------------- persistent GRU recurrence ----------------
static __device__ __forceinline__ void gridbar(int* bar, int& epoch) {
  __syncthreads();              // compiler drains vmcnt before s_barrier
  ++epoch;
  if (threadIdx.x == 0) {
    __hip_atomic_fetch_add(bar, 1, __ATOMIC_RELAXED, __HIP_MEMORY_SCOPE_AGENT);
    while (__hip_atomic_load(bar, __ATOMIC_RELAXED, __HIP_MEMORY_SCOPE_AGENT) < epoch * NB_)
      __builtin_amdgcn_s_sleep(1);
  }
  __syncthreads();
}

// dynamic LDS layout (bytes):
//   [0)       w1h  32 units * 1024 = 32768
//   [32768)   w1l  32768
//   [65536)   w2h  24 units * 1024 = 24576
//   [90112)   w2l  24576            -> 114688
//   [114688)  ls_rz float[4][16][16] 4096
//   [118784)  ls_gi float[4][16][8]  2048
//   [120832)  ls_gh float[4][16][8]  2048  -> total 122880
#define RNN_LDS 122880

__global__ __launch_bounds__(256, 1) void k_rnn(
    const u16* __restrict__ w1h, const u16* __restrict__ w1l,
    const u16* __restrict__ w2h, const u16* __restrict__ w2l,
    const float* __restrict__ gix,
    const float* __restrict__ bhh,
    const float* __restrict__ mbih, const float* __restrict__ mbhh,
    const float* __restrict__ cm,
    float* __restrict__ hs, float* __restrict__ hms,
    u32* __restrict__ hpk,       // packed (hi|lo<<16) task-h   [31][2][64][256]
    u32* __restrict__ apk,       // packed (hi|lo<<16) meta-h   [1920][256] (b*30+s)
    int* bar) {
  extern __shared__ char smem[];
  u16* lw1h = (u16*)smem;
  u16* lw1l = (u16*)(smem + 32768);
  u16* lw2h = (u16*)(smem + 65536);
  u16* lw2l = (u16*)(smem + 90112);
  float* ls_rz = (float*)(smem + 114688);  // [(w*16+rl)*16+c]
  float* ls_gi = (float*)(smem + 118784);  // [(w*16+rl)*8+c]
  float* ls_gh = (float*)(smem + 120832);

  const int blk = blockIdx.x;
  const int tid = threadIdx.x;
  const int lane = tid & 63;
  const int w = tid >> 6;
  const int t1 = blk >> 5;
  const int hd1 = (blk & 31) * 8;
  const int hd2 = blk * 4;
  const int arow = w * 16 + (lane & 15);
  const int ko = (lane >> 4) * 8;
  int epoch = 0;

  // one-time: weights -> LDS
  {
    const uint4* s1h = (const uint4*)(w1h + (size_t)blk * 40 * 512);
    const uint4* s1l = (const uint4*)(w1l + (size_t)blk * 40 * 512);
    uint4* d1h = (uint4*)lw1h; uint4* d1l = (uint4*)lw1l;
    for (int i = tid; i < 2048; i += 256) { d1h[i] = s1h[i]; d1l[i] = s1l[i]; }
    const uint4* s2h = (const uint4*)(w2h + (size_t)blk * 24 * 512);
    const uint4* s2l = (const uint4*)(w2l + (size_t)blk * 24 * 512);
    uint4* d2h = (uint4*)lw2h; uint4* d2l = (uint4*)lw2l;
    for (int i = tid; i < 1536; i += 256) { d2h[i] = s2h[i]; d2l[i] = s2l[i]; }
  }
  // hoisted per-thread constants
  const int cc = lane & 15;
  float bhhn = (cc < 8) ? bhh[t1 * 768 + 512 + hd1 + cc] : 0.f;
  float mrz_b = 0.f, mgi_b = 0.f, mgh_b = 0.f;
  if (cc < 8) {
    int gc = (cc < 4) ? (hd2 + cc) : (256 + hd2 + (cc - 4));
    mrz_b = mbih[gc] + mbhh[gc];
  } else if (cc < 12) {
    int gn = 512 + hd2 + (cc - 8);
    mgi_b = mbih[gn];
    mgh_b = mbhh[gn];
  }
  __syncthreads();

  short8 ah1[8], al1[8];   // apk[s-1] chunks (G1, reused by m2)
  short8 xh2[8], xl2[8];   // own-task hpk[s] chunks (loaded in m1, reused by G2)

  for (int s = 0; s < 30; ++s) {
    // ---------- phase 1: task GRUs ----------
    f32x4 a1[2], a2[2];
    #pragma unroll
    for (int i = 0; i < 2; ++i) {
      a1[i] = (f32x4){0.f, 0.f, 0.f, 0.f};
      a2[i] = (f32x4){0.f, 0.f, 0.f, 0.f};
    }
    if (s > 0) {
      const u32* Ap = apk + (size_t)(arow * 30 + (s - 1)) * 256;
      #pragma unroll
      for (int k = 0; k < 8; ++k) aload8(Ap + k * 32 + ko, ah1[k], al1[k]);
      #pragma unroll
      for (int k = 0; k < 8; ++k) {
        #pragma unroll
        for (int nt = 0; nt < 2; ++nt) {
          short8 bh = *(const short8*)(lw1h + (k * 2 + nt) * 512 + lane * 8);
          short8 bl = *(const short8*)(lw1l + (k * 2 + nt) * 512 + lane * 8);
          a1[nt] = mfma16(ah1[k], bh, a1[nt]);
          a1[nt] = mfma16(al1[k], bh, a1[nt]);
          a1[nt] = mfma16(ah1[k], bl, a1[nt]);
          short8 bh2 = *(const short8*)(lw1h + ((8 + k) * 2 + nt) * 512 + lane * 8);
          short8 bl2 = *(const short8*)(lw1l + ((8 + k) * 2 + nt) * 512 + lane * 8);
          a2[nt] = mfma16(xh2[k], bh2, a2[nt]);
          a2[nt] = mfma16(xl2[k], bh2, a2[nt]);
          a2[nt] = mfma16(xh2[k], bl2, a2[nt]);
        }
      }
    }
    // gates -> LDS (C layout: row=(l>>4)*4+i, col=l&15)
    {
      const float* grow = gix + (size_t)(blk * 30 + s) * 64 * 32;
      #pragma unroll
      for (int i = 0; i < 4; ++i) {
        int rl = (lane >> 4) * 4 + i;
        int r = w * 16 + rl;
        ls_rz[(w * 16 + rl) * 16 + cc] = a1[0][i] + a2[0][i] + grow[r * 32 + cc];
        if (cc < 8) {
          ls_gi[(w * 16 + rl) * 8 + cc] = a1[1][i] + grow[r * 32 + 16 + cc];
          ls_gh[(w * 16 + rl) * 8 + cc] = a2[1][i] + bhhn;
        }
      }
    }
    __syncthreads();
    #pragma unroll
    for (int p = 0; p < 2; ++p) {
      int item = p * 64 + lane;
      int rl = item >> 3, c = item & 7;
      float rv = ls_rz[(w * 16 + rl) * 16 + c], zv = ls_rz[(w * 16 + rl) * 16 + 8 + c];
      float gi = ls_gi[(w * 16 + rl) * 8 + c], gh = ls_gh[(w * 16 + rl) * 8 + c];
      float r = 1.f / (1.f + expf(-rv));
      float z = 1.f / (1.f + expf(-zv));
      float n = tanhf(gi + r * gh);
      int b = w * 16 + rl;
      int hd = hd1 + c;
      int io = ((s * 2 + t1) * 64 + b) * 256 + hd;
      int oo = (((s + 1) * 2 + t1) * 64 + b) * 256 + hd;
      float hold = hs[io];
      float m = cm[(s * 2 + t1) * 64 + b];
      float hnew = (1.f - z) * n + z * hold;
      float hout = (m > 0.5f) ? hnew : hold;
      hs[oo] = hout;
      u16 xh, xl; split_bf16(hout, xh, xl);
      astore(hpk + oo, (u32)xh | ((u32)xl << 16));
    }
    gridbar(bar, epoch);

    // ---------- phase 2: meta GRU ----------
    f32x4 m1 = (f32x4){0.f, 0.f, 0.f, 0.f};
    f32x4 m2 = (f32x4){0.f, 0.f, 0.f, 0.f};
    // own-task hpk[s+1] chunks -> retained regs (reused next step by G2)
    {
      const u32* Hp = hpk + (size_t)(((s + 1) * 2 + t1) * 64 + arow) * 256;
      #pragma unroll
      for (int k = 0; k < 8; ++k) aload8(Hp + k * 32 + ko, xh2[k], xl2[k]);
      short8 yh[8], yl[8];
      const u32* Hq = hpk + (size_t)(((s + 1) * 2 + (1 - t1)) * 64 + arow) * 256;
      #pragma unroll
      for (int k = 0; k < 8; ++k) aload8(Hq + k * 32 + ko, yh[k], yl[k]);
      #pragma unroll
      for (int k = 0; k < 8; ++k) {
        short8 bh = *(const short8*)(lw2h + k * 512 + lane * 8);
        short8 bl = *(const short8*)(lw2l + k * 512 + lane * 8);
        m1 = mfma16(xh2[k], bh, m1);
        m1 = mfma16(xl2[k], bh, m1);
        m1 = mfma16(xh2[k], bl, m1);
      }
      #pragma unroll
      for (int k = 0; k < 8; ++k) {
        short8 bh = *(const short8*)(lw2h + (8 + k) * 512 + lane * 8);
        short8 bl = *(const short8*)(lw2l + (8 + k) * 512 + lane * 8);
        m1 = mfma16(yh[k], bh, m1);
        m1 = mfma16(yl[k], bh, m1);
        m1 = mfma16(yh[k], bl, m1);
      }
    }
    if (s > 0) {
      #pragma unroll
      for (int k = 0; k < 8; ++k) {
        short8 bh = *(const short8*)(lw2h + (16 + k) * 512 + lane * 8);
        short8 bl = *(const short8*)(lw2l + (16 + k) * 512 + lane * 8);
        m2 = mfma16(ah1[k], bh, m2);
        m2 = mfma16(al1[k], bh, m2);
        m2 = mfma16(ah1[k], bl, m2);
      }
    }
    #pragma unroll
    for (int i = 0; i < 4; ++i) {
      int rl = (lane >> 4) * 4 + i;
      if (cc < 8) {
        ls_rz[(w * 16 + rl) * 16 + cc] = m1[i] + m2[i] + mrz_b;
      } else if (cc < 12) {
        ls_gi[(w * 16 + rl) * 8 + (cc - 8)] = m1[i] + mgi_b;
        ls_gh[(w * 16 + rl) * 8 + (cc - 8)] = m2[i] + mgh_b;
      }
    }
    __syncthreads();
    {
      int rl = lane >> 2, c = lane & 3;
      float rv = ls_rz[(w * 16 + rl) * 16 + c], zv = ls_rz[(w * 16 + rl) * 16 + 4 + c];
      float gi = ls_gi[(w * 16 + rl) * 8 + c], gh = ls_gh[(w * 16 + rl) * 8 + c];
      float r = 1.f / (1.f + expf(-rv));
      float z = 1.f / (1.f + expf(-zv));
      float n = tanhf(gi + r * gh);
      int b = w * 16 + rl;
      int g2 = hd2 + c;
      float hmold = hms[(s * 64 + b) * 256 + g2];
      float hmnew = (1.f - z) * n + z * hmold;
      hms[((s + 1) * 64 + b) * 256 + g2] = hmnew;
      int ar = b * 30 + s;
      u16 xh, xl; split_bf16(hmnew, xh, xl);
      astore(apk + ar * 256 + g2, (u32)xh | ((u32)xl << 16));
    }
    gridbar(bar, epoch);
  }
}

// ---------------- score_new GEMM: [1920,256] x [256,20000] (3-pass split bf16) ----------------
__global__ __launch_bounds__(256) void k_gnew(const u32* __restrict__ apk,
                                              const u16* __restrict__ wnh, const u16* __restrict__ wnl,
                                              const float* __restrict__ bnew,
                                              float* __restrict__ out) {
  int bid = blockIdx.x;
  int mb = bid / 157, nb = bid % 157;
  int tid = threadIdx.x, lane = tid & 63, w = tid >> 6;
  int ko = (lane >> 4) * 8;
  f32x4 acc[2][8];
  #pragma unroll
  for (int mi = 0; mi < 2; ++mi)
    #pragma unroll
    for (int nt = 0; nt < 8; ++nt) acc[mi][nt] = (f32x4){0.f, 0.f, 0.f, 0.f};
  #pragma unroll
  for (int ks = 0; ks < 8; ++ks) {
    short8 ah[2], al[2];
    #pragma unroll
    for (int mi = 0; mi < 2; ++mi) {
      int r = mb * 128 + (w * 2 + mi) * 16 + (lane & 15);
      const u32* p = apk + (size_t)r * 256 + ks * 32 + ko;
      uint4 w0 = *(const uint4*)p;
      uint4 w1v = *(const uint4*)(p + 4);
      u32 wb[8] = {w0.x, w0.y, w0.z, w0.w, w1v.x, w1v.y, w1v.z, w1v.w};
      #pragma unroll
      for (int j = 0; j < 8; ++j) {
        ah[mi][j] = (short)(wb[j] & 0xffffu);
        al[mi][j] = (short)(wb[j] >> 16);
      }
    }
    #pragma unroll
    for (int nt = 0; nt < 8; ++nt) {
      int un = (nb * 8 + nt) * 8 + ks;
      short8 bh = *(const short8*)(wnh + (size_t)un * 512 + lane * 8);
      short8 bl = *(const short8*)(wnl + (size_t)un * 512 + lane * 8);
      #pragma unroll
      for (int mi = 0; mi < 2; ++mi) {
        acc[mi][nt] = mfma16(ah[mi], bh, acc[mi][nt]);
        acc[mi][nt] = mfma16(al[mi], bh, acc[mi][nt]);
        acc[mi][nt] = mfma16(ah[mi], bl, acc[mi][nt]);
      }
    }
  }
  #pragma unroll
  for (int mi = 0; mi < 2; ++mi)
    #pragma unroll
    for (int nt = 0; nt < 8; ++nt) {
      int col = nb * 128 + nt * 16 + (lane & 15);
      if (col < 20000) {
        float bn = bnew[col];
        #pragma unroll
        for (int i = 0; i < 4; ++i) {
          int r = mb * 128 + (w * 2 + mi) * 16 + (lane >> 4) * 4 + i;
          out[(size_t)r * 20000 + col] = acc[mi][nt][i] + bn;
        }
      }
    }
}

// ---------------- sparse copy scores: one wave per (t,b,s) ----------------
__global__ __launch_bounds__(64) void k_copy(const float* __restrict__ hs,
                                             const int* __restrict__ cv,
                                             const float* __restrict__ wc,
                                             const float* __restrict__ bc,
                                             float* __restrict__ out) {
  int u = blockIdx.x;                 // t*1920 + b*30 + s
  int t = u / 1920;
  int rem = u % 1920;
  int b = rem / 30, s = rem % 30;
  int lane = threadIdx.x;
  const float* hp = hs + (size_t)(((s + 1) * 2 + t) * 64 + b) * 256;
  float4 h4 = *(const float4*)(hp + lane * 4);
  int base = u * 20;
  for (int c = 0; c < 20; ++c) {
    int idx = cv[base + c];
    const float* wr = wc + ((size_t)t * 20000 + idx) * 256;
    float4 w4 = *(const float4*)(wr + lane * 4);
    float d = h4.x * w4.x + h4.y * w4.y + h4.z * w4.z + h4.w * w4.w;
    #pragma unroll
    for (int m = 32; m >= 1; m >>= 1) d += __shfl_xor(d, m, 64);
    if (lane == 0)
      out[(size_t)(1 + t) * 38400000 + (size_t)(b * 30 + s) * 20000 + idx] = d + bc[t * 20000 + idx];
  }
}

extern "C" void kernel_launch(void* const* d_in, const int* in_sizes, int n_in,
                              void* d_out, int out_size, void* d_ws, size_t ws_size,
                              hipStream_t stream) {
  const int* iv = (const int*)d_in[1];
  const int* cv = (const int*)d_in[2];
  const float* emb = (const float*)d_in[3];
  const float* Wih = (const float*)d_in[4];
  const float* Whh = (const float*)d_in[5];
  const float* bih = (const float*)d_in[6];
  const float* bhh = (const float*)d_in[7];
  const float* mWih = (const float*)d_in[8];
  const float* mWhh = (const float*)d_in[9];
  const float* mbih = (const float*)d_in[10];
  const float* mbhh = (const float*)d_in[11];
  const float* Wnew = (const float*)d_in[12];
  const float* bnew = (const float*)d_in[13];
  const float* Wcopy = (const float*)d_in[14];
  const float* bcopy = (const float*)d_in[15];
  float* out = (float*)d_out;
  char* ws = (char*)d_ws;

  size_t o = 0;
  auto take = [&](size_t sz) { size_t r = o; o += sz; return r; };
  size_t BAR = take(256);
  size_t CM  = take(15360);
  size_t EBH = take(983040);
  size_t EBL = take(983040);
  size_t HS  = take(4063232);    // fp32 h_seq [31][2][64][256]
  size_t HMS = take(2031616);    // fp32 hm_seq [31][64][256]
  size_t HPK = take(4063232);    // packed bf16 hi|lo task-h [31][2][64][256] u32
  size_t APK = take(1966080);    // packed bf16 hi|lo meta-h [1920][256] u32
  size_t GIX = take(15728640);   // fp32 gi_x [64 blk][30][64][32]
  size_t W1H = take(2621440);
  size_t W1L = take(2621440);
  size_t W2H = take(1572864);
  size_t W2L = take(1572864);
  size_t WNH = take(10289152);
  size_t WNL = take(10289152);
  if (ws_size < o) return;   // insufficient workspace: fail loudly via absmax

  hipFuncSetAttribute(reinterpret_cast<const void*>(k_rnn),
                      hipFuncAttributeMaxDynamicSharedMemorySize, RNN_LDS);

  // zero barrier + step-0 state + sparse output region
  hipMemsetAsync(ws + BAR, 0, 256, stream);
  hipMemsetAsync(ws + HS, 0, 131072, stream);
  hipMemsetAsync(ws + HMS, 0, 65536, stream);
  hipMemsetAsync((char*)d_out + 153600000, 0, 307200000, stream);

  k_pool<<<3840, 128, 0, stream>>>(iv, emb, (u16*)(ws + EBH), (u16*)(ws + EBL), (float*)(ws + CM));
  k_swz<<<3536, 256, 0, stream>>>(Wih, Whh, mWih, mWhh, Wnew,
                                  (u16*)(ws + W1H), (u16*)(ws + W1L),
                                  (u16*)(ws + W2H), (u16*)(ws + W2L),
                                  (u16*)(ws + WNH), (u16*)(ws + WNL));
  k_gix<<<64, 256, 0, stream>>>((const u16*)(ws + EBH), (const u16*)(ws + EBL),
                                (const u16*)(ws + W1H), (const u16*)(ws + W1L),
                                bih, bhh, (float*)(ws + GIX));
  k_rnn<<<NB_, 256, RNN_LDS, stream>>>((const u16*)(ws + W1H), (const u16*)(ws + W1L),
                                       (const u16*)(ws + W2H), (const u16*)(ws + W2L),
                                       (const float*)(ws + GIX), bhh, mbih, mbhh,
                                       (const float*)(ws + CM),
                                       (float*)(ws + HS), (float*)(ws + HMS),
                                       (u32*)(ws + HPK), (u32*)(ws + APK),
                                       (int*)(ws + BAR));
  k_gnew<<<2355, 256, 0, stream>>>((const u32*)(ws + APK),
                                   (const u16*)(ws + WNH), (const u16*)(ws + WNL),
                                   bnew, out);
  k_copy<<<3840, 64, 0, stream>>>((const float*)(ws + HS), cv, Wcopy, bcopy, out);
}

// Round 4
// 697.247 us; speedup vs baseline: 2.1477x; 1.2476x over previous
//
#include <hip/hip_runtime.h>

typedef unsigned short u16;
typedef unsigned int u32;
typedef unsigned long long u64;
typedef __attribute__((ext_vector_type(8))) short short8;
typedef __attribute__((ext_vector_type(4))) float f32x4;

#define NB_ 64

static __device__ __forceinline__ f32x4 mfma16(short8 a, short8 b, f32x4 c) {
  return __builtin_amdgcn_mfma_f32_16x16x32_bf16(a, b, c, 0, 0, 0);
}

// split fp32 -> bf16 hi + bf16 lo  (x ~= hi + lo, residual ~2^-17 * |x|)
static __device__ __forceinline__ void split_bf16(float x, u16& hi, u16& lo) {
  unsigned u = __float_as_uint(x);
  unsigned r = (u + 0x7fffu + ((u >> 16) & 1u)) >> 16;
  hi = (u16)r;
  float fh = __uint_as_float(r << 16);
  float xl = x - fh;
  unsigned ul = __float_as_uint(xl);
  unsigned rl2 = (ul + 0x7fffu + ((ul >> 16) & 1u)) >> 16;
  lo = (u16)rl2;
}

// write-through publication store (agent-visible after vmcnt drain; proven r1-r3)
static __device__ __forceinline__ void astore(u32* p, u32 v) {
  __hip_atomic_store(p, v, __ATOMIC_RELAXED, __HIP_MEMORY_SCOPE_AGENT);
}
// normal (cached, coalesced) load of 8 packed elems; freshness via buffer_inv at barrier
static __device__ __forceinline__ void vload8(const u32* p, short8& h, short8& l) {
  uint4 a = *(const uint4*)p;
  uint4 b = *(const uint4*)(p + 4);
  u32 wb[8] = {a.x, a.y, a.z, a.w, b.x, b.y, b.z, b.w};
  #pragma unroll
  for (int j = 0; j < 8; ++j) {
    h[j] = (short)(wb[j] & 0xffffu);
    l[j] = (short)(wb[j] >> 16);
  }
}
static __device__ __forceinline__ float unpack_hl(u32 pk) {
  return __uint_as_float((pk & 0xffffu) << 16) + __uint_as_float(pk & 0xffff0000u);
}

// ---------------- pooling: emb gather + mean over valid items ----------------
__global__ __launch_bounds__(128) void k_pool(const int* __restrict__ iv,
                                              const float* __restrict__ emb,
                                              u16* __restrict__ ebh, u16* __restrict__ ebl,
                                              float* __restrict__ cm) {
  int u = blockIdx.x;             // u = (s*2+t)*64+b
  int s = u >> 7;
  int t = (u >> 6) & 1;
  int b = u & 63;
  int d = threadIdx.x;
  const int ibase = ((t * 64 + b) * 30 + s) * 12;
  float sum = 0.f;
  int cnt = 0;
  for (int k = 0; k < 12; ++k) {
    int idx = iv[ibase + k];
    if (idx > 0) { cnt++; sum += emb[(size_t)idx * 128 + d]; }
  }
  float den = (cnt > 0) ? (float)cnt : 1.f;
  float v = sum / den;
  u16 hi, lo; split_bf16(v, hi, lo);
  ebh[(size_t)u * 128 + d] = hi;
  ebl[(size_t)u * 128 + d] = lo;
  if (d == 0) cm[u] = (cnt > 0) ? 1.f : 0.f;
}

// ---------------- weight swizzle into MFMA B-fragment layout ----------------
// B-frag (16x16x32): lane l holds B[k=(l>>4)*8+j][n=l&15], j=0..7
// w1: 64 blk * 20 ks * 2 nt; ks 0..7 WihH(K=256), 8..15 Whh(K=256), 16..19 WihX(K=128)
// w2: 64 blk * 24 ks; ks 0..7 mWih OWN task (t1=blk>>5), 8..15 mWih other task, 16..23 mWhh
__global__ __launch_bounds__(256) void k_swz(const float* __restrict__ Wih,
                                             const float* __restrict__ Whh,
                                             const float* __restrict__ mWih,
                                             const float* __restrict__ mWhh,
                                             const float* __restrict__ Wnew,
                                             u16* __restrict__ w1h, u16* __restrict__ w1l,
                                             u16* __restrict__ w2h, u16* __restrict__ w2l,
                                             u16* __restrict__ wnh, u16* __restrict__ wnl) {
  int gu = blockIdx.x * 4 + (threadIdx.x >> 6);
  int lane = threadIdx.x & 63;
  int ko = (lane >> 4) * 8;
  int cl = lane & 15;
  float src[8];
  if (gu < 2560) {
    int blk = gu / 40, r = gu % 40, ksIdx = r >> 1, nt = r & 1;
    int t = blk >> 5, hd0 = (blk & 31) * 8;
    int c = nt * 16 + cl;
    if (c < 24) {
      int gc = (c < 8) ? (hd0 + c) : (c < 16) ? (256 + hd0 + (c - 8)) : (512 + hd0 + (c - 16));
      const float* wrow; int kk;
      if (ksIdx < 8)       { wrow = Wih + (size_t)(t * 768 + gc) * 384 + 128; kk = ksIdx * 32 + ko; }
      else if (ksIdx < 16) { wrow = Whh + (size_t)(t * 768 + gc) * 256;       kk = (ksIdx - 8) * 32 + ko; }
      else                 { wrow = Wih + (size_t)(t * 768 + gc) * 384;       kk = (ksIdx - 16) * 32 + ko; }
      #pragma unroll
      for (int j = 0; j < 8; ++j) src[j] = wrow[kk + j];
    } else {
      #pragma unroll
      for (int j = 0; j < 8; ++j) src[j] = 0.f;
    }
    int off = gu * 512 + lane * 8;
    #pragma unroll
    for (int j = 0; j < 8; ++j) { u16 h, l; split_bf16(src[j], h, l); w1h[off + j] = h; w1l[off + j] = l; }
  } else if (gu < 4096) {
    int g2 = gu - 2560;
    int blk = g2 / 24, ksIdx = g2 % 24;
    int t1 = blk >> 5;
    int hd0 = blk * 4;
    int c = cl;
    if (c < 12) {
      int gc = (c < 4) ? (hd0 + c) : (c < 8) ? (256 + hd0 + (c - 4)) : (512 + hd0 + (c - 8));
      if (ksIdx < 16) {
        int chunk = (ksIdx < 8) ? (t1 * 8 + ksIdx) : ((1 - t1) * 8 + (ksIdx - 8));
        int kk = chunk * 32 + ko;
        #pragma unroll
        for (int j = 0; j < 8; ++j) src[j] = mWih[(size_t)gc * 512 + kk + j];
      } else {
        int kk = (ksIdx - 16) * 32 + ko;
        #pragma unroll
        for (int j = 0; j < 8; ++j) src[j] = mWhh[(size_t)gc * 256 + kk + j];
      }
    } else {
      #pragma unroll
      for (int j = 0; j < 8; ++j) src[j] = 0.f;
    }
    int off = g2 * 512 + lane * 8;
    #pragma unroll
    for (int j = 0; j < 8; ++j) { u16 h, l; split_bf16(src[j], h, l); w2h[off + j] = h; w2l[off + j] = l; }
  } else if (gu < 14144) {
    int g3 = gu - 4096;
    int gnt = g3 >> 3, ks = g3 & 7;
    int col = gnt * 16 + cl;
    if (col < 20000) {
      int kk = ks * 32 + ko;
      #pragma unroll
      for (int j = 0; j < 8; ++j) src[j] = Wnew[(size_t)col * 256 + kk + j];
    } else {
      #pragma unroll
      for (int j = 0; j < 8; ++j) src[j] = 0.f;
    }
    int off = g3 * 512 + lane * 8;
    #pragma unroll
    for (int j = 0; j < 8; ++j) { u16 h, l; split_bf16(src[j], h, l); wnh[off + j] = h; wnl[off + j] = l; }
  }
}

// ---------------- gi_x precompute: gi_x = x @ WihX^T (+bias folds) ----------------
// layout: gix[blk][s][row 0..63][32]: cols 0..15 = r,z (+bih+bhh), 16..23 = n (+bih)
__global__ __launch_bounds__(256) void k_gix(const u16* __restrict__ ebh, const u16* __restrict__ ebl,
                                             const u16* __restrict__ w1h, const u16* __restrict__ w1l,
                                             const float* __restrict__ bih, const float* __restrict__ bhh,
                                             float* __restrict__ gix) {
  int blk = blockIdx.x;
  int t1 = blk >> 5, hd1 = (blk & 31) * 8;
  int tid = threadIdx.x, lane = tid & 63, w = tid >> 6;
  int arow = w * 16 + (lane & 15);
  int ko = (lane >> 4) * 8;
  __shared__ u16 lwh[4096], lwl[4096];
  {
    const uint4* sh = (const uint4*)(w1h + ((size_t)blk * 40 + 32) * 512);
    const uint4* sl = (const uint4*)(w1l + ((size_t)blk * 40 + 32) * 512);
    uint4* dh = (uint4*)lwh; uint4* dl = (uint4*)lwl;
    for (int i = tid; i < 512; i += 256) { dh[i] = sh[i]; dl[i] = sl[i]; }
  }
  int c = lane & 15;
  float brz, bn = 0.f;
  {
    int gc = (c < 8) ? (hd1 + c) : (256 + hd1 + (c - 8));
    brz = bih[t1 * 768 + gc] + bhh[t1 * 768 + gc];
    if (c < 8) bn = bih[t1 * 768 + 512 + hd1 + c];
  }
  __syncthreads();
  for (int s = 0; s < 30; ++s) {
    f32x4 a3[2];
    a3[0] = (f32x4){0.f, 0.f, 0.f, 0.f};
    a3[1] = (f32x4){0.f, 0.f, 0.f, 0.f};
    const u16* Xh = ebh + (size_t)((s * 2 + t1) * 64 + arow) * 128;
    const u16* Xl = ebl + (size_t)((s * 2 + t1) * 64 + arow) * 128;
    #pragma unroll
    for (int k = 0; k < 4; ++k) {
      short8 xh = *(const short8*)(Xh + k * 32 + ko);
      short8 xl = *(const short8*)(Xl + k * 32 + ko);
      #pragma unroll
      for (int nt = 0; nt < 2; ++nt) {
        short8 bh = *(const short8*)(lwh + (k * 2 + nt) * 512 + lane * 8);
        short8 bl = *(const short8*)(lwl + (k * 2 + nt) * 512 + lane * 8);
        a3[nt] = mfma16(xh, bh, a3[nt]);
        a3[nt] = mfma16(xl, bh, a3[nt]);
        a3[nt] = mfma16(xh, bl, a3[nt]);
      }
    }
    float* grow = gix + (size_t)(blk * 30 + s) * 64 * 32;
    #pragma unroll
    for (int i = 0; i < 4; ++i) {
      int r = w * 16 + (lane >> 4) * 4 + i;
      grow[r * 32 + c] = a3[0][i] + brz;
      if (c < 8) grow[r * 32 + 16 + c] = a3[1][i] + bn;
    }
  }
}

// ---------------- persistent GRU recurrence ----------------
// Flag-array barrier: slot per block (128B apart). Arrival = relaxed agent store
// of epoch to own slot; wave 0 lanes poll one slot each (read-shared, no RMW).
// After all flags seen: buffer_inv sc1 (acquire-agent) so subsequent NORMAL
// cached loads observe other blocks' write-through stores.
static __device__ __forceinline__ void gridbar(u32* slots, int blk, int& epoch) {
  __syncthreads();              // drains vmcnt: publication stores complete
  ++epoch;
  int tid = threadIdx.x;
  if (tid == 0)
    astore(slots + blk * 32, (u32)epoch);
  if (tid < 64) {
    while (__hip_atomic_load(slots + tid * 32, __ATOMIC_RELAXED, __HIP_MEMORY_SCOPE_AGENT) < (u32)epoch)
      __builtin_amdgcn_s_sleep(1);
  }
  asm volatile("buffer_inv sc1" ::: "memory");
  __syncthreads();
}

// dynamic LDS layout (bytes):
//   [0)       w1h  32 units * 1024 = 32768
//   [32768)   w1l  32768
//   [65536)   w2h  24 units * 1024 = 24576
//   [90112)   w2l  24576            -> 114688
//   [114688)  ls_rz float[4][16][16] 4096
//   [118784)  ls_gi float[4][16][8]  2048
//   [120832)  ls_gh float[4][16][8]  2048  -> total 122880
#define RNN_LDS 122880

__global__ __launch_bounds__(256, 1) void k_rnn(
    const u16* __restrict__ w1h, const u16* __restrict__ w1l,
    const u16* __restrict__ w2h, const u16* __restrict__ w2l,
    const float* __restrict__ gix,
    const float* __restrict__ bhh,
    const float* __restrict__ mbih, const float* __restrict__ mbhh,
    const float* __restrict__ cm,
    u32* __restrict__ hpk,       // packed (hi|lo<<16) task-h   [31][2][64][256]
    u32* __restrict__ apk,       // packed (hi|lo<<16) meta-h   [1920][256] (b*30+s)
    u32* slots) {
  extern __shared__ char smem[];
  u16* lw1h = (u16*)smem;
  u16* lw1l = (u16*)(smem + 32768);
  u16* lw2h = (u16*)(smem + 65536);
  u16* lw2l = (u16*)(smem + 90112);
  float* ls_rz = (float*)(smem + 114688);  // [(w*16+rl)*16+c]
  float* ls_gi = (float*)(smem + 118784);  // [(w*16+rl)*8+c]
  float* ls_gh = (float*)(smem + 120832);

  const int blk = blockIdx.x;
  const int tid = threadIdx.x;
  const int lane = tid & 63;
  const int w = tid >> 6;
  const int t1 = blk >> 5;
  const int hd1 = (blk & 31) * 8;
  const int hd2 = blk * 4;
  const int arow = w * 16 + (lane & 15);
  const int ko = (lane >> 4) * 8;
  int epoch = 0;

  // one-time: weights -> LDS
  {
    const uint4* s1h = (const uint4*)(w1h + (size_t)blk * 40 * 512);
    const uint4* s1l = (const uint4*)(w1l + (size_t)blk * 40 * 512);
    uint4* d1h = (uint4*)lw1h; uint4* d1l = (uint4*)lw1l;
    for (int i = tid; i < 2048; i += 256) { d1h[i] = s1h[i]; d1l[i] = s1l[i]; }
    const uint4* s2h = (const uint4*)(w2h + (size_t)blk * 24 * 512);
    const uint4* s2l = (const uint4*)(w2l + (size_t)blk * 24 * 512);
    uint4* d2h = (uint4*)lw2h; uint4* d2l = (uint4*)lw2l;
    for (int i = tid; i < 1536; i += 256) { d2h[i] = s2h[i]; d2l[i] = s2l[i]; }
  }
  // hoisted per-thread constants
  const int cc = lane & 15;
  float bhhn = (cc < 8) ? bhh[t1 * 768 + 512 + hd1 + cc] : 0.f;
  float mrz_b = 0.f, mgi_b = 0.f, mgh_b = 0.f;
  if (cc < 8) {
    int gc = (cc < 4) ? (hd2 + cc) : (256 + hd2 + (cc - 4));
    mrz_b = mbih[gc] + mbhh[gc];
  } else if (cc < 12) {
    int gn = 512 + hd2 + (cc - 8);
    mgi_b = mbih[gn];
    mgh_b = mbhh[gn];
  }
  __syncthreads();

  short8 ah1[8], al1[8];   // apk[s-1] chunks (G1, reused by m2)
  short8 xh2[8], xl2[8];   // own-task hpk[s] chunks (loaded in m1, reused by G2)

  for (int s = 0; s < 30; ++s) {
    // ---------- phase 1: task GRUs ----------
    f32x4 a1[2], a2[2];
    #pragma unroll
    for (int i = 0; i < 2; ++i) {
      a1[i] = (f32x4){0.f, 0.f, 0.f, 0.f};
      a2[i] = (f32x4){0.f, 0.f, 0.f, 0.f};
    }
    if (s > 0) {
      const u32* Ap = apk + (size_t)(arow * 30 + (s - 1)) * 256;
      #pragma unroll
      for (int k = 0; k < 8; ++k) vload8(Ap + k * 32 + ko, ah1[k], al1[k]);
      #pragma unroll
      for (int k = 0; k < 8; ++k) {
        #pragma unroll
        for (int nt = 0; nt < 2; ++nt) {
          short8 bh = *(const short8*)(lw1h + (k * 2 + nt) * 512 + lane * 8);
          short8 bl = *(const short8*)(lw1l + (k * 2 + nt) * 512 + lane * 8);
          a1[nt] = mfma16(ah1[k], bh, a1[nt]);
          a1[nt] = mfma16(al1[k], bh, a1[nt]);
          a1[nt] = mfma16(ah1[k], bl, a1[nt]);
          short8 bh2 = *(const short8*)(lw1h + ((8 + k) * 2 + nt) * 512 + lane * 8);
          short8 bl2 = *(const short8*)(lw1l + ((8 + k) * 2 + nt) * 512 + lane * 8);
          a2[nt] = mfma16(xh2[k], bh2, a2[nt]);
          a2[nt] = mfma16(xl2[k], bh2, a2[nt]);
          a2[nt] = mfma16(xh2[k], bl2, a2[nt]);
        }
      }
    }
    // gates -> LDS (C layout: row=(l>>4)*4+i, col=l&15)
    {
      const float* grow = gix + (size_t)(blk * 30 + s) * 64 * 32;
      #pragma unroll
      for (int i = 0; i < 4; ++i) {
        int rl = (lane >> 4) * 4 + i;
        int r = w * 16 + rl;
        ls_rz[(w * 16 + rl) * 16 + cc] = a1[0][i] + a2[0][i] + grow[r * 32 + cc];
        if (cc < 8) {
          ls_gi[(w * 16 + rl) * 8 + cc] = a1[1][i] + grow[r * 32 + 16 + cc];
          ls_gh[(w * 16 + rl) * 8 + cc] = a2[1][i] + bhhn;
        }
      }
    }
    __syncthreads();
    #pragma unroll
    for (int p = 0; p < 2; ++p) {
      int item = p * 64 + lane;
      int rl = item >> 3, c = item & 7;
      float rv = ls_rz[(w * 16 + rl) * 16 + c], zv = ls_rz[(w * 16 + rl) * 16 + 8 + c];
      float gi = ls_gi[(w * 16 + rl) * 8 + c], gh = ls_gh[(w * 16 + rl) * 8 + c];
      float r = 1.f / (1.f + expf(-rv));
      float z = 1.f / (1.f + expf(-zv));
      float n = tanhf(gi + r * gh);
      int b = w * 16 + rl;
      int hd = hd1 + c;
      int io = ((s * 2 + t1) * 64 + b) * 256 + hd;
      int oo = (((s + 1) * 2 + t1) * 64 + b) * 256 + hd;
      float hold = unpack_hl(hpk[io]);     // own block wrote it last step; fresh post-inv
      float m = cm[(s * 2 + t1) * 64 + b];
      float hnew = (1.f - z) * n + z * hold;
      float hout = (m > 0.5f) ? hnew : hold;
      u16 xh, xl; split_bf16(hout, xh, xl);
      astore(hpk + oo, (u32)xh | ((u32)xl << 16));
    }
    gridbar(slots, blk, epoch);

    // ---------- phase 2: meta GRU ----------
    f32x4 m1 = (f32x4){0.f, 0.f, 0.f, 0.f};
    f32x4 m2 = (f32x4){0.f, 0.f, 0.f, 0.f};
    // own-task hpk[s+1] chunks -> retained regs (reused next step by G2)
    {
      const u32* Hp = hpk + (size_t)(((s + 1) * 2 + t1) * 64 + arow) * 256;
      #pragma unroll
      for (int k = 0; k < 8; ++k) vload8(Hp + k * 32 + ko, xh2[k], xl2[k]);
      short8 yh[8], yl[8];
      const u32* Hq = hpk + (size_t)(((s + 1) * 2 + (1 - t1)) * 64 + arow) * 256;
      #pragma unroll
      for (int k = 0; k < 8; ++k) vload8(Hq + k * 32 + ko, yh[k], yl[k]);
      #pragma unroll
      for (int k = 0; k < 8; ++k) {
        short8 bh = *(const short8*)(lw2h + k * 512 + lane * 8);
        short8 bl = *(const short8*)(lw2l + k * 512 + lane * 8);
        m1 = mfma16(xh2[k], bh, m1);
        m1 = mfma16(xl2[k], bh, m1);
        m1 = mfma16(xh2[k], bl, m1);
      }
      #pragma unroll
      for (int k = 0; k < 8; ++k) {
        short8 bh = *(const short8*)(lw2h + (8 + k) * 512 + lane * 8);
        short8 bl = *(const short8*)(lw2l + (8 + k) * 512 + lane * 8);
        m1 = mfma16(yh[k], bh, m1);
        m1 = mfma16(yl[k], bh, m1);
        m1 = mfma16(yh[k], bl, m1);
      }
    }
    if (s > 0) {
      #pragma unroll
      for (int k = 0; k < 8; ++k) {
        short8 bh = *(const short8*)(lw2h + (16 + k) * 512 + lane * 8);
        short8 bl = *(const short8*)(lw2l + (16 + k) * 512 + lane * 8);
        m2 = mfma16(ah1[k], bh, m2);
        m2 = mfma16(al1[k], bh, m2);
        m2 = mfma16(ah1[k], bl, m2);
      }
    }
    #pragma unroll
    for (int i = 0; i < 4; ++i) {
      int rl = (lane >> 4) * 4 + i;
      if (cc < 8) {
        ls_rz[(w * 16 + rl) * 16 + cc] = m1[i] + m2[i] + mrz_b;
      } else if (cc < 12) {
        ls_gi[(w * 16 + rl) * 8 + (cc - 8)] = m1[i] + mgi_b;
        ls_gh[(w * 16 + rl) * 8 + (cc - 8)] = m2[i] + mgh_b;
      }
    }
    __syncthreads();
    {
      int rl = lane >> 2, c = lane & 3;
      float rv = ls_rz[(w * 16 + rl) * 16 + c], zv = ls_rz[(w * 16 + rl) * 16 + 4 + c];
      float gi = ls_gi[(w * 16 + rl) * 8 + c], gh = ls_gh[(w * 16 + rl) * 8 + c];
      float r = 1.f / (1.f + expf(-rv));
      float z = 1.f / (1.f + expf(-zv));
      float n = tanhf(gi + r * gh);
      int b = w * 16 + rl;
      int g2 = hd2 + c;
      float hmold = (s > 0) ? unpack_hl(apk[(b * 30 + (s - 1)) * 256 + g2]) : 0.f;
      float hmnew = (1.f - z) * n + z * hmold;
      int ar = b * 30 + s;
      u16 xh, xl; split_bf16(hmnew, xh, xl);
      astore(apk + ar * 256 + g2, (u32)xh | ((u32)xl << 16));
    }
    gridbar(slots, blk, epoch);
  }
}

// ---------------- score_new GEMM: [1920,256] x [256,20000] (3-pass split bf16) ----------------
__global__ __launch_bounds__(256) void k_gnew(const u32* __restrict__ apk,
                                              const u16* __restrict__ wnh, const u16* __restrict__ wnl,
                                              const float* __restrict__ bnew,
                                              float* __restrict__ out) {
  int bid = blockIdx.x;
  int mb = bid / 157, nb = bid % 157;
  int tid = threadIdx.x, lane = tid & 63, w = tid >> 6;
  int ko = (lane >> 4) * 8;
  f32x4 acc[2][8];
  #pragma unroll
  for (int mi = 0; mi < 2; ++mi)
    #pragma unroll
    for (int nt = 0; nt < 8; ++nt) acc[mi][nt] = (f32x4){0.f, 0.f, 0.f, 0.f};
  #pragma unroll
  for (int ks = 0; ks < 8; ++ks) {
    short8 ah[2], al[2];
    #pragma unroll
    for (int mi = 0; mi < 2; ++mi) {
      int r = mb * 128 + (w * 2 + mi) * 16 + (lane & 15);
      vload8(apk + (size_t)r * 256 + ks * 32 + ko, ah[mi], al[mi]);
    }
    #pragma unroll
    for (int nt = 0; nt < 8; ++nt) {
      int un = (nb * 8 + nt) * 8 + ks;
      short8 bh = *(const short8*)(wnh + (size_t)un * 512 + lane * 8);
      short8 bl = *(const short8*)(wnl + (size_t)un * 512 + lane * 8);
      #pragma unroll
      for (int mi = 0; mi < 2; ++mi) {
        acc[mi][nt] = mfma16(ah[mi], bh, acc[mi][nt]);
        acc[mi][nt] = mfma16(al[mi], bh, acc[mi][nt]);
        acc[mi][nt] = mfma16(ah[mi], bl, acc[mi][nt]);
      }
    }
  }
  #pragma unroll
  for (int mi = 0; mi < 2; ++mi)
    #pragma unroll
    for (int nt = 0; nt < 8; ++nt) {
      int col = nb * 128 + nt * 16 + (lane & 15);
      if (col < 20000) {
        float bn = bnew[col];
        #pragma unroll
        for (int i = 0; i < 4; ++i) {
          int r = mb * 128 + (w * 2 + mi) * 16 + (lane >> 4) * 4 + i;
          out[(size_t)r * 20000 + col] = acc[mi][nt][i] + bn;
        }
      }
    }
}

// ---------------- sparse copy scores: one wave per (t,b,s) ----------------
__global__ __launch_bounds__(64) void k_copy(const u32* __restrict__ hpk,
                                             const int* __restrict__ cv,
                                             const float* __restrict__ wc,
                                             const float* __restrict__ bc,
                                             float* __restrict__ out) {
  int u = blockIdx.x;                 // t*1920 + b*30 + s
  int t = u / 1920;
  int rem = u % 1920;
  int b = rem / 30, s = rem % 30;
  int lane = threadIdx.x;
  const u32* hp = hpk + (size_t)(((s + 1) * 2 + t) * 64 + b) * 256;
  uint4 hq = *(const uint4*)(hp + lane * 4);
  float4 h4;
  h4.x = unpack_hl(hq.x); h4.y = unpack_hl(hq.y);
  h4.z = unpack_hl(hq.z); h4.w = unpack_hl(hq.w);
  int base = u * 20;
  for (int c = 0; c < 20; ++c) {
    int idx = cv[base + c];
    const float* wr = wc + ((size_t)t * 20000 + idx) * 256;
    float4 w4 = *(const float4*)(wr + lane * 4);
    float d = h4.x * w4.x + h4.y * w4.y + h4.z * w4.z + h4.w * w4.w;
    #pragma unroll
    for (int m = 32; m >= 1; m >>= 1) d += __shfl_xor(d, m, 64);
    if (lane == 0)
      out[(size_t)(1 + t) * 38400000 + (size_t)(b * 30 + s) * 20000 + idx] = d + bc[t * 20000 + idx];
  }
}

extern "C" void kernel_launch(void* const* d_in, const int* in_sizes, int n_in,
                              void* d_out, int out_size, void* d_ws, size_t ws_size,
                              hipStream_t stream) {
  const int* iv = (const int*)d_in[1];
  const int* cv = (const int*)d_in[2];
  const float* emb = (const float*)d_in[3];
  const float* Wih = (const float*)d_in[4];
  const float* Whh = (const float*)d_in[5];
  const float* bih = (const float*)d_in[6];
  const float* bhh = (const float*)d_in[7];
  const float* mWih = (const float*)d_in[8];
  const float* mWhh = (const float*)d_in[9];
  const float* mbih = (const float*)d_in[10];
  const float* mbhh = (const float*)d_in[11];
  const float* Wnew = (const float*)d_in[12];
  const float* bnew = (const float*)d_in[13];
  const float* Wcopy = (const float*)d_in[14];
  const float* bcopy = (const float*)d_in[15];
  float* out = (float*)d_out;
  char* ws = (char*)d_ws;

  size_t o = 0;
  auto take = [&](size_t sz) { size_t r = o; o += sz; return r; };
  size_t BAR = take(8192);       // 64 slots * 128B
  size_t CM  = take(15360);
  size_t EBH = take(983040);
  size_t EBL = take(983040);
  size_t HPK = take(4063232);    // packed bf16 hi|lo task-h [31][2][64][256] u32
  size_t APK = take(1966080);    // packed bf16 hi|lo meta-h [1920][256] u32
  size_t GIX = take(15728640);   // fp32 gi_x [64 blk][30][64][32]
  size_t W1H = take(2621440);
  size_t W1L = take(2621440);
  size_t W2H = take(1572864);
  size_t W2L = take(1572864);
  size_t WNH = take(10289152);
  size_t WNL = take(10289152);
  if (ws_size < o) return;   // insufficient workspace: fail loudly via absmax

  hipFuncSetAttribute(reinterpret_cast<const void*>(k_rnn),
                      hipFuncAttributeMaxDynamicSharedMemorySize, RNN_LDS);

  // zero barrier slots + step-0 state + sparse output region
  hipMemsetAsync(ws + BAR, 0, 8192, stream);
  hipMemsetAsync(ws + HPK, 0, 131072, stream);
  hipMemsetAsync((char*)d_out + 153600000, 0, 307200000, stream);

  k_pool<<<3840, 128, 0, stream>>>(iv, emb, (u16*)(ws + EBH), (u16*)(ws + EBL), (float*)(ws + CM));
  k_swz<<<3536, 256, 0, stream>>>(Wih, Whh, mWih, mWhh, Wnew,
                                  (u16*)(ws + W1H), (u16*)(ws + W1L),
                                  (u16*)(ws + W2H), (u16*)(ws + W2L),
                                  (u16*)(ws + WNH), (u16*)(ws + WNL));
  k_gix<<<64, 256, 0, stream>>>((const u16*)(ws + EBH), (const u16*)(ws + EBL),
                                (const u16*)(ws + W1H), (const u16*)(ws + W1L),
                                bih, bhh, (float*)(ws + GIX));
  k_rnn<<<NB_, 256, RNN_LDS, stream>>>((const u16*)(ws + W1H), (const u16*)(ws + W1L),
                                       (const u16*)(ws + W2H), (const u16*)(ws + W2L),
                                       (const float*)(ws + GIX), bhh, mbih, mbhh,
                                       (const float*)(ws + CM),
                                       (u32*)(ws + HPK), (u32*)(ws + APK),
                                       (u32*)(ws + BAR));
  k_gnew<<<2355, 256, 0, stream>>>((const u32*)(ws + APK),
                                   (const u16*)(ws + WNH), (const u16*)(ws + WNL),
                                   bnew, out);
  k_copy<<<3840, 64, 0, stream>>>((const u32*)(ws + HPK), cv, Wcopy, bcopy, out);
}